// Round 6
// baseline (286.505 us; speedup 1.0000x reference)
//
#include <hip/hip_runtime.h>
#include <hip/hip_bf16.h>
#include <math.h>

#define NQ 4096
#define CC 256

typedef __attribute__((ext_vector_type(8))) short bfrag;
typedef __attribute__((ext_vector_type(4))) float ffrag;

__device__ inline unsigned short f2bf(float x) {
  __hip_bfloat16 h = __float2bfloat16(x);
  return *reinterpret_cast<unsigned short*>(&h);
}

__device__ inline void gload16(const void* g, void* l) {
  __builtin_amdgcn_global_load_lds(
      (const __attribute__((address_space(1))) void*)g,
      (__attribute__((address_space(3))) void*)l, 16, 0, 0);
}

// ================================================================= prep mega
__device__ void tr64(const float* __restrict__ src,
                     unsigned short* __restrict__ dstb, int Cin, int P,
                     int p0, int c0, int b, float (*t)[73]) {
  int tid = threadIdx.x;
  int rx = tid & 15, ry = tid >> 4;
  const float* Sb = src + (size_t)b * Cin * P + p0 + rx * 4;
  #pragma unroll
  for (int i = 0; i < 4; i++) {
    int r = ry + i * 16;
    float4 v = *(const float4*)(Sb + (size_t)(c0 + r) * P);
    t[r][rx * 4 + 0] = v.x; t[r][rx * 4 + 1] = v.y;
    t[r][rx * 4 + 2] = v.z; t[r][rx * 4 + 3] = v.w;
  }
  __syncthreads();
  size_t ob = (size_t)b * P * Cin;
  #pragma unroll
  for (int i = 0; i < 4; i++) {
    int pr = ry + i * 16;
    float x0 = t[rx * 4 + 0][pr], x1 = t[rx * 4 + 1][pr];
    float x2 = t[rx * 4 + 2][pr], x3 = t[rx * 4 + 3][pr];
    size_t idx = ob + (size_t)(p0 + pr) * Cin + c0 + rx * 4;
    ushort4 u4;
    u4.x = f2bf(x0); u4.y = f2bf(x1); u4.z = f2bf(x2); u4.w = f2bf(x3);
    *(ushort4*)(dstb + idx) = u4;
  }
}

__global__ __launch_bounds__(256)
void prep_all_k(const float* S, const float* f0, const float* f1, const float* f2,
                const float* q_w, const float* off_w, const float* wgt_w,
                const float* vw0, const float* vw1, const float* vw2,
                const float* out_w, const float* fc1_w, const float* fc2_w,
                const float* off_b, const float* wgt_b,
                unsigned short* Sbf,
                unsigned short* Xf0, unsigned short* Xf1, unsigned short* Xf2,
                unsigned short* q_wb, unsigned short* owb,
                unsigned short* vw0b, unsigned short* vw1b, unsigned short* vw2b,
                unsigned short* out_wb, unsigned short* fc1_wb,
                unsigned short* fc2_wb, float* bias144) {
  __shared__ float t[64][73];
  int bid = blockIdx.x;
  if (bid < 512) {
    int l = bid;
    tr64(S, Sbf, 256, 4096, (l & 63) * 64, ((l >> 6) & 3) * 64, l >> 8, t);
  } else if (bid < 1024) {
    int l = bid - 512;
    tr64(f0, Xf0, 256, 4096, (l & 63) * 64, ((l >> 6) & 3) * 64, l >> 8, t);
  } else if (bid < 1280) {
    int l = bid - 1024;
    tr64(f1, Xf1, 512, 1024, (l & 15) * 64, ((l >> 4) & 7) * 64, l >> 7, t);
  } else if (bid < 1408) {
    int l = bid - 1280;
    tr64(f2, Xf2, 1024, 256, (l & 3) * 64, ((l >> 2) & 15) * 64, l >> 6, t);
  } else if (bid < 2688) {
    int i4 = (bid - 1408) * 256 + threadIdx.x;
    const float* src; unsigned short* dst;
    if (i4 < 16384)       { src = q_w;   dst = q_wb; }
    else if (i4 < 32768)  { i4 -= 16384;  src = vw0;   dst = vw0b; }
    else if (i4 < 65536)  { i4 -= 32768;  src = vw1;   dst = vw1b; }
    else if (i4 < 131072) { i4 -= 65536;  src = vw2;   dst = vw2b; }
    else if (i4 < 196608) { i4 -= 131072; src = out_w; dst = out_wb; }
    else if (i4 < 262144) { i4 -= 196608; src = fc1_w; dst = fc1_wb; }
    else                  { i4 -= 262144; src = fc2_w; dst = fc2_wb; }
    float4 v = ((const float4*)src)[i4];
    ushort4 u; u.x = f2bf(v.x); u.y = f2bf(v.y); u.z = f2bf(v.z); u.w = f2bf(v.w);
    ((ushort4*)dst)[i4] = u;
  } else {
    int e = (bid - 2688) * 256 + threadIdx.x;
    float v = (e < 24576) ? off_w[e] : (e < 36864 ? wgt_w[e - 24576] : 0.f);
    owb[e] = f2bf(v);
    if (e < 96) bias144[e] = off_b[e];
    else if (e < 144) bias144[e] = wgt_b[e - 96];
  }
}

// ================================================================= GEMM body
// BK=64 k-major LDS. Kloop iterations; lda/ldb are full row strides.
// EPI 0: fp32+bias  1: GELU->bf16+bias  3: bf16+bias  4: fp32 no bias (partial)
template<int BM, int BN, int WM, int WN, int EPI>
__device__ __forceinline__ void gemm_body(
    const unsigned short* __restrict__ A, const unsigned short* __restrict__ B,
    const float* __restrict__ bias, float* __restrict__ outf,
    unsigned short* __restrict__ outb, int N, int Kloop, int lda, int ldb,
    int ldo, int m0, int n0, unsigned short* As, unsigned short* Bs) {
  constexpr int MI = BM / (WM * 16), NI = BN / (WN * 16);
  constexpr int TA = BM / 8, TB = BN / 8;
  constexpr int LBM = (BM == 32) ? 5 : (BM == 64) ? 6 : 7;
  constexpr int LBN = (BN == 64) ? 6 : (BN == 128) ? 7 : 8;
  int tid = threadIdx.x, wave = tid >> 6, lane = tid & 63;
  int quad = lane >> 4, l16 = lane & 15;
  int wm = wave / WN, wn = wave % WN;
  const int mbase = wm * (BM / WM), nbase = wn * (BN / WN);

  ffrag acc[MI][NI];
  #pragma unroll
  for (int i = 0; i < MI; i++)
    #pragma unroll
    for (int j = 0; j < NI; j++) acc[i][j] = (ffrag)0.f;

  for (int k0 = 0; k0 < Kloop; k0 += 64) {
    __syncthreads();
    for (int t = wave; t < TA + TB; t += 4) {
      if (t < TA) {
        int s = t * 64 + lane;
        int kc = s >> LBM, r = s & (BM - 1);
        gload16(A + (size_t)(m0 + r) * lda + k0 + kc * 8, (char*)As + t * 1024);
      } else {
        int s = (t - TA) * 64 + lane;
        int kc = s >> LBN, r = s & (BN - 1);
        gload16(B + (size_t)(n0 + r) * ldb + k0 + kc * 8, (char*)Bs + (t - TA) * 1024);
      }
    }
    __syncthreads();
    #pragma unroll
    for (int ks = 0; ks < 2; ks++) {
      bfrag af[MI], bf[NI];
      #pragma unroll
      for (int mi = 0; mi < MI; mi++)
        af[mi] = *(const bfrag*)(As + ((((ks * 4 + quad) << LBM) + mbase + mi * 16 + l16) << 3));
      #pragma unroll
      for (int ni = 0; ni < NI; ni++)
        bf[ni] = *(const bfrag*)(Bs + ((((ks * 4 + quad) << LBN) + nbase + ni * 16 + l16) << 3));
      #pragma unroll
      for (int mi = 0; mi < MI; mi++)
        #pragma unroll
        for (int ni = 0; ni < NI; ni++)
          acc[mi][ni] = __builtin_amdgcn_mfma_f32_16x16x32_bf16(
              af[mi], bf[ni], acc[mi][ni], 0, 0, 0);
    }
  }

  #pragma unroll
  for (int mi = 0; mi < MI; mi++) {
    int mrow = m0 + mbase + mi * 16 + quad * 4;
    #pragma unroll
    for (int ni = 0; ni < NI; ni++) {
      int n = n0 + nbase + ni * 16 + l16;
      if (n < N) {
        float bv = (EPI == 4) ? 0.f : bias[n];
        #pragma unroll
        for (int r = 0; r < 4; r++) {
          float v = acc[mi][ni][r] + bv;
          if (EPI == 1) {
            v = 0.5f * v * (1.f + erff(v * 0.70710678118654752f));
            outb[(size_t)(mrow + r) * ldo + n] = f2bf(v);
          } else if (EPI == 3) {
            outb[(size_t)(mrow + r) * ldo + n] = f2bf(v);
          } else {
            outf[(size_t)(mrow + r) * ldo + n] = v;
          }
        }
      }
    }
  }
}

// ================================================================= Q GEMM+LN
__device__ __forceinline__ void gemm_ln_q(
    const unsigned short* __restrict__ A, const unsigned short* __restrict__ B,
    const float* __restrict__ bias, unsigned short* __restrict__ outb,
    const float* __restrict__ g, const float* __restrict__ be,
    int m0, char* sm) {
  unsigned short* As = (unsigned short*)sm;
  unsigned short* Bs = (unsigned short*)(sm + 4096);
  float* L = (float*)sm;
  const int K = 256;

  int tid = threadIdx.x, wave = tid >> 6, lane = tid & 63;
  int quad = lane >> 4, l16 = lane & 15;

  ffrag acc[2][4];
  #pragma unroll
  for (int i = 0; i < 2; i++)
    #pragma unroll
    for (int j = 0; j < 4; j++) acc[i][j] = (ffrag)0.f;

  for (int k0 = 0; k0 < K; k0 += 64) {
    __syncthreads();
    for (int t = wave; t < 36; t += 4) {
      if (t < 4) {
        int s = t * 64 + lane;
        int kc = s >> 5, r = s & 31;
        gload16(A + (size_t)(m0 + r) * K + k0 + kc * 8, sm + t * 1024);
      } else {
        int s = (t - 4) * 64 + lane;
        int kc = s >> 8, r = s & 255;
        gload16(B + (size_t)r * K + k0 + kc * 8, sm + 4096 + (t - 4) * 1024);
      }
    }
    __syncthreads();
    #pragma unroll
    for (int ks = 0; ks < 2; ks++) {
      bfrag af[2], bf[4];
      #pragma unroll
      for (int mi = 0; mi < 2; mi++)
        af[mi] = *(const bfrag*)(As + ((((ks * 4 + quad) << 5) + mi * 16 + l16) << 3));
      #pragma unroll
      for (int ni = 0; ni < 4; ni++)
        bf[ni] = *(const bfrag*)(Bs + ((((ks * 4 + quad) << 8) + wave * 64 + ni * 16 + l16) << 3));
      #pragma unroll
      for (int mi = 0; mi < 2; mi++)
        #pragma unroll
        for (int ni = 0; ni < 4; ni++)
          acc[mi][ni] = __builtin_amdgcn_mfma_f32_16x16x32_bf16(
              af[mi], bf[ni], acc[mi][ni], 0, 0, 0);
    }
  }
  __syncthreads();

  #pragma unroll
  for (int mi = 0; mi < 2; mi++) {
    int row = mi * 16 + quad * 4;
    #pragma unroll
    for (int ni = 0; ni < 4; ni++) {
      int col = wave * 64 + ni * 16 + l16;
      float bv = bias[col];
      #pragma unroll
      for (int r = 0; r < 4; r++)
        L[(row + r) * 264 + col] = acc[mi][ni][r] + bv;
    }
  }
  __syncthreads();

  int row = tid >> 3, j = tid & 7;
  int seg = ((j + row) & 7) * 32;
  const float* Lr = L + row * 264 + seg;
  float s1 = 0.f, s2 = 0.f;
  #pragma unroll
  for (int i = 0; i < 8; i++) {
    float4 t4 = *(const float4*)(Lr + i * 4);
    s1 += t4.x + t4.y + t4.z + t4.w;
    s2 += t4.x * t4.x + t4.y * t4.y + t4.z * t4.z + t4.w * t4.w;
  }
  #pragma unroll
  for (int o = 1; o < 8; o <<= 1) {
    s1 += __shfl_xor(s1, o);
    s2 += __shfl_xor(s2, o);
  }
  float mu = s1 * (1.f / 256.f);
  float var = s2 * (1.f / 256.f) - mu * mu;
  float rs = rsqrtf(var + 1e-5f);
  int gm = m0 + row;
  #pragma unroll
  for (int i = 0; i < 8; i++) {
    int col = seg + i * 4;
    float4 t4 = *(const float4*)(Lr + i * 4);
    float4 gg = *(const float4*)(g + col);
    float4 bb4 = *(const float4*)(be + col);
    ushort4 ub;
    ub.x = f2bf((t4.x - mu) * rs * gg.x + bb4.x);
    ub.y = f2bf((t4.y - mu) * rs * gg.y + bb4.y);
    ub.z = f2bf((t4.z - mu) * rs * gg.z + bb4.z);
    ub.w = f2bf((t4.w - mu) * rs * gg.w + bb4.w);
    *(ushort4*)(outb + (size_t)gm * CC + col) = ub;
  }
}

// ================================================================= kernels
// qv: [0,256) Q-LN | [256,512) V0 | [512,640) V1 split2 | [640,704) V2 split4
__global__ __launch_bounds__(256)
void qv_k(const unsigned short* Sbf, const unsigned short* q_wb, const float* q_b,
          const float* lnq_g, const float* lnq_b, unsigned short* Qbf,
          const unsigned short* Xf0, const unsigned short* Xf1,
          const unsigned short* Xf2, const unsigned short* vw0b,
          const unsigned short* vw1b, const unsigned short* vw2b,
          const float* vb0, unsigned short* V0b, float* Vp1, float* Vp2) {
  __shared__ __attribute__((aligned(16))) char sm[36864];
  int bid = blockIdx.x;
  unsigned short* As = (unsigned short*)sm;
  unsigned short* Bs = (unsigned short*)(sm + 8192);
  if (bid < 256) {
    gemm_ln_q(Sbf, q_wb, q_b, Qbf, lnq_g, lnq_b, bid * 32, sm);
  } else if (bid < 512) {
    int t = bid - 256;
    gemm_body<64, 128, 2, 2, 3>(Xf0, vw0b, vb0, nullptr, V0b, 256, 256, 256, 256,
                                256, (t >> 1) * 64, (t & 1) * 128, As, Bs);
  } else if (bid < 640) {
    int l = bid - 512, ks = l >> 6, t = l & 63;
    gemm_body<64, 128, 2, 2, 4>(Xf1 + ks * 256, vw1b + ks * 256, nullptr,
                                Vp1 + (size_t)ks * 524288, nullptr, 256, 256, 512, 512,
                                256, (t >> 1) * 64, (t & 1) * 128, As, Bs);
  } else {
    int l = bid - 640, ks = l >> 4, t = l & 15;
    gemm_body<64, 128, 2, 2, 4>(Xf2 + ks * 256, vw2b + ks * 256, nullptr,
                                Vp2 + (size_t)ks * 131072, nullptr, 256, 256, 1024, 1024,
                                256, (t >> 1) * 64, (t & 1) * 128, As, Bs);
  }
}

// offv: [0,256) offwgt GEMM | [256,768) V1 reduce | [768,896) V2 reduce
__global__ __launch_bounds__(256)
void offv_k(const unsigned short* Qbf, const unsigned short* owb,
            const float* bias144, float* offwgt,
            const float* Vp1, const float* Vp2, const float* vb1,
            const float* vb2, unsigned short* V1b, unsigned short* V2b) {
  __shared__ __attribute__((aligned(16))) unsigned short As[4096];
  __shared__ __attribute__((aligned(16))) unsigned short Bs[8192];
  int bid = blockIdx.x;
  if (bid < 256) {
    gemm_body<64, 128, 2, 2, 0>(Qbf, owb, bias144, offwgt, nullptr, 144, 256, 256,
                                256, 144, (bid >> 1) * 64, (bid & 1) * 128, As, Bs);
  } else if (bid < 768) {
    int e4 = (bid - 256) * 256 + threadIdx.x;       // [0, 131072)
    const float4* P = (const float4*)Vp1;
    float4 a = P[e4], b = P[e4 + 131072];
    float4 bb = *(const float4*)(vb1 + ((e4 << 2) & 255));
    ushort4 u;
    u.x = f2bf(a.x + b.x + bb.x); u.y = f2bf(a.y + b.y + bb.y);
    u.z = f2bf(a.z + b.z + bb.z); u.w = f2bf(a.w + b.w + bb.w);
    ((ushort4*)V1b)[e4] = u;
  } else {
    int e4 = (bid - 768) * 256 + threadIdx.x;       // [0, 32768)
    const float4* P = (const float4*)Vp2;
    float4 a = P[e4], b = P[e4 + 32768], c = P[e4 + 65536], d = P[e4 + 98304];
    float4 bb = *(const float4*)(vb2 + ((e4 << 2) & 255));
    ushort4 u;
    u.x = f2bf(a.x + b.x + c.x + d.x + bb.x);
    u.y = f2bf(a.y + b.y + c.y + d.y + bb.y);
    u.z = f2bf(a.z + b.z + c.z + d.z + bb.z);
    u.w = f2bf(a.w + b.w + c.w + d.w + bb.w);
    ((ushort4*)V2b)[e4] = u;
  }
}

// outA: split-K=4 GEMM acc@out_w -> fp32 partials [4][8192][256]
__global__ __launch_bounds__(256)
void outA_k(const unsigned short* accbf, const unsigned short* out_wb, float* Op) {
  __shared__ __attribute__((aligned(16))) char sm[36864];
  int ks = blockIdx.y;
  gemm_body<32, 256, 1, 4, 4>(accbf + ks * 256, out_wb + ks * 256, nullptr,
                              Op + (size_t)ks * 2097152, nullptr, 256, 256, 1024,
                              1024, 256, blockIdx.x * 32, 0,
                              (unsigned short*)sm, (unsigned short*)(sm + 4096));
}

// outB: reduce 4 partials + bias + S residual + LN -> Zf fp32, Zbf bf16
__global__ __launch_bounds__(256)
void outB_k(const float* __restrict__ Op, const float* __restrict__ S,
            const float* __restrict__ out_b, const float* __restrict__ g,
            const float* __restrict__ be, float* __restrict__ Zf,
            unsigned short* __restrict__ Zbf) {
  __shared__ float Ls[16][264];
  int q0 = blockIdx.x * 16;
  int b = q0 >> 12, qq = q0 & (NQ - 1);
  int t = threadIdx.x;
  {
    int cs = t >> 2, j = (t & 3) * 4;
    #pragma unroll
    for (int c0 = 0; c0 < 256; c0 += 64) {
      float4 sv = *(const float4*)(S + (((size_t)(b * 256 + c0 + cs)) << 12) + qq + j);
      Ls[j + 0][c0 + cs] = sv.x; Ls[j + 1][c0 + cs] = sv.y;
      Ls[j + 2][c0 + cs] = sv.z; Ls[j + 3][c0 + cs] = sv.w;
    }
  }
  __syncthreads();
  int c = t;
  float bv = out_b[c];
  float val[16];
  #pragma unroll
  for (int r = 0; r < 16; r++) {
    size_t idx = (size_t)(q0 + r) * 256 + c;
    val[r] = Op[idx] + Op[idx + 2097152] + Op[idx + 4194304] + Op[idx + 6291456]
           + bv + Ls[r][c];
  }
  __syncthreads();
  #pragma unroll
  for (int r = 0; r < 16; r++) Ls[r][c] = val[r];
  __syncthreads();
  int row = t >> 4, lg = t & 15;
  const float* Lr = &Ls[row][lg * 16];
  float s1 = 0.f, s2 = 0.f;
  #pragma unroll
  for (int i = 0; i < 4; i++) {
    float4 t4 = *(const float4*)(Lr + i * 4);
    s1 += t4.x + t4.y + t4.z + t4.w;
    s2 += t4.x * t4.x + t4.y * t4.y + t4.z * t4.z + t4.w * t4.w;
  }
  #pragma unroll
  for (int o = 1; o < 16; o <<= 1) {
    s1 += __shfl_xor(s1, o);
    s2 += __shfl_xor(s2, o);
  }
  float mu = s1 * (1.f / 256.f);
  float var = s2 * (1.f / 256.f) - mu * mu;
  float rs = rsqrtf(var + 1e-5f);
  int gm = q0 + row;
  #pragma unroll
  for (int i = 0; i < 4; i++) {
    int col = lg * 16 + i * 4;
    float4 t4 = *(const float4*)(Lr + i * 4);
    float4 gg = *(const float4*)(g + col);
    float4 bb4 = *(const float4*)(be + col);
    float4 y;
    y.x = (t4.x - mu) * rs * gg.x + bb4.x;
    y.y = (t4.y - mu) * rs * gg.y + bb4.y;
    y.z = (t4.z - mu) * rs * gg.z + bb4.z;
    y.w = (t4.w - mu) * rs * gg.w + bb4.w;
    *(float4*)(Zf + (size_t)gm * CC + col) = y;
    ushort4 ub;
    ub.x = f2bf(y.x); ub.y = f2bf(y.y); ub.z = f2bf(y.z); ub.w = f2bf(y.w);
    *(ushort4*)(Zbf + (size_t)gm * CC + col) = ub;
  }
}

__global__ __launch_bounds__(256)
void fc1_k(const unsigned short* Zbf, const unsigned short* fc1_wb,
           const float* fc1_b, unsigned short* hbf) {
  __shared__ __attribute__((aligned(16))) unsigned short As[4096];
  __shared__ __attribute__((aligned(16))) unsigned short Bs[8192];
  gemm_body<64, 128, 2, 2, 1>(Zbf, fc1_wb, fc1_b, nullptr, hbf, 1024, 256, 256,
                              256, 1024, blockIdx.y * 64, blockIdx.x * 128, As, Bs);
}

// fc2A: split-K=4 -> fp32 partials [4][8192][256]
__global__ __launch_bounds__(256)
void fc2A_k(const unsigned short* hbf, const unsigned short* fc2_wb, float* Fp) {
  __shared__ __attribute__((aligned(16))) char sm[36864];
  int ks = blockIdx.y;
  gemm_body<32, 256, 1, 4, 4>(hbf + ks * 256, fc2_wb + ks * 256, nullptr,
                              Fp + (size_t)ks * 2097152, nullptr, 256, 256, 1024,
                              1024, 256, blockIdx.x * 32, 0,
                              (unsigned short*)sm, (unsigned short*)(sm + 4096));
}

// fc2B: reduce 4 partials + bias + Z residual, transposed store to out
__global__ __launch_bounds__(256)
void fc2B_k(const float* __restrict__ Fp, const float* __restrict__ Z,
            const float* __restrict__ fc2_b, float* __restrict__ outp) {
  int q0 = blockIdx.x * 64;
  int b = q0 >> 12, qq = q0 & (NQ - 1);
  int n = threadIdx.x;
  float bv = fc2_b[n];
  float* od = outp + (((size_t)(b * 256 + n)) << 12) + qq;
  #pragma unroll
  for (int g4 = 0; g4 < 16; g4++) {
    float4 o;
    #pragma unroll
    for (int j = 0; j < 4; j++) {
      size_t idx = (size_t)(q0 + g4 * 4 + j) * 256 + n;
      float v = Fp[idx] + Fp[idx + 2097152] + Fp[idx + 4194304] + Fp[idx + 6291456]
              + Z[idx] + bv;
      ((float*)&o)[j] = v;
    }
    *(float4*)(od + g4 * 4) = o;
  }
}

// ================================================================= sampling
__global__ __launch_bounds__(256)
void sample_k(const float* __restrict__ ow, const float* __restrict__ sim,
              const unsigned short* __restrict__ V0, const unsigned short* __restrict__ V1,
              const unsigned short* __restrict__ V2, unsigned short* __restrict__ acc) {
  int bn = blockIdx.x;
  int q = ((bn & 7) << 10) | (bn >> 3);
  int b = q >> 12, n = q & (NQ - 1);
  int tid = threadIdx.x, head = tid >> 6, lane = tid & 63;
  int half = lane >> 5, l32 = lane & 31;

  __shared__ float s_w[48];
  __shared__ int   s_xy[48][2];
  __shared__ float s_f[48][2];
  __shared__ uint2 s_ow[192];

  if (tid < 48) {
    int hh = tid / 12, pt = tid % 12, l = pt >> 2, mm = pt & 3;
    int oidx = (hh * 3 + l) * 4 + mm;
    float offx = ow[(size_t)q * 144 + oidx * 2 + 0];
    float offy = ow[(size_t)q * 144 + oidx * 2 + 1];
    float refx = ((n & 63) + 0.5f) * (1.f / 64.f);
    float refy = ((n >> 6) + 0.5f) * (1.f / 64.f);
    float gx = tanhf((refx + offx) * 2.f - 1.f);
    float gy = tanhf((refy + offy) * 2.f - 1.f);
    gx = fminf(1.f, fmaxf(-1.f, gx));
    gy = fminf(1.f, fmaxf(-1.f, gy));
    int Wl = 64 >> l;
    float x = (gx + 1.f) * 0.5f * (float)(Wl - 1);
    float y = (gy + 1.f) * 0.5f * (float)(Wl - 1);
    float x0 = floorf(x), y0 = floorf(y);
    s_xy[tid][0] = (int)x0;
    s_xy[tid][1] = (int)y0;
    s_f[tid][0] = x - x0;
    s_f[tid][1] = y - y0;
    s_w[tid] = ow[(size_t)q * 144 + 96 + oidx] * (sim[q] + 0.001f);
  }
  __syncthreads();
  if (tid < 4) {
    float mx = -1e30f;
    #pragma unroll
    for (int i = 0; i < 12; i++) mx = fmaxf(mx, s_w[tid * 12 + i]);
    float e[12], ssum = 0.f;
    #pragma unroll
    for (int i = 0; i < 12; i++) { e[i] = expf(s_w[tid * 12 + i] - mx); ssum += e[i]; }
    float inv = 1.f / ssum;
    #pragma unroll
    for (int i = 0; i < 12; i++) s_w[tid * 12 + i] = e[i] * inv;
  }
  __syncthreads();
  if (tid < 192) {
    int s = tid >> 2, tap = tid & 3;
    int l = (s % 12) >> 2;
    int Wl = 64 >> l;
    int X = s_xy[s][0] + (tap & 1), Y = s_xy[s][1] + (tap >> 1);
    bool valid = (X >= 0 && X < Wl && Y >= 0 && Y < Wl);
    float wx = (tap & 1) ? s_f[s][0] : 1.f - s_f[s][0];
    float wy = (tap >> 1) ? s_f[s][1] : 1.f - s_f[s][1];
    float twt = valid ? s_w[s] * wx * wy : 0.f;
    int Xc = min(max(X, 0), Wl - 1), Yc = min(max(Y, 0), Wl - 1);
    s_ow[tid].x = (unsigned)((Yc * Wl + Xc) << 8);
    s_ow[tid].y = __float_as_uint(twt);
  }
  __syncthreads();

  const unsigned short* B0 = V0 + (size_t)b * 4096 * CC;
  const unsigned short* B1 = V1 + (size_t)b * 1024 * CC;
  const unsigned short* B2 = V2 + (size_t)b * 256 * CC;
  int ch8 = l32 * 8;
  float a0 = 0.f, a1 = 0.f, a2 = 0.f, a3 = 0.f;
  float a4 = 0.f, a5 = 0.f, a6 = 0.f, a7 = 0.f;
  #pragma unroll
  for (int it = 0; it < 24; it++) {
    const unsigned short* base = (it < 8) ? B0 : (it < 16) ? B1 : B2;
    uint2 owv = s_ow[head * 48 + it * 2 + half];
    float w = __uint_as_float(owv.y);
    const uint4 u = *(const uint4*)(base + owv.x + ch8);
    a0 = fmaf(w, __uint_as_float(u.x << 16), a0);
    a1 = fmaf(w, __uint_as_float(u.x & 0xffff0000u), a1);
    a2 = fmaf(w, __uint_as_float(u.y << 16), a2);
    a3 = fmaf(w, __uint_as_float(u.y & 0xffff0000u), a3);
    a4 = fmaf(w, __uint_as_float(u.z << 16), a4);
    a5 = fmaf(w, __uint_as_float(u.z & 0xffff0000u), a5);
    a6 = fmaf(w, __uint_as_float(u.w << 16), a6);
    a7 = fmaf(w, __uint_as_float(u.w & 0xffff0000u), a7);
  }
  a0 += __shfl_xor(a0, 32); a1 += __shfl_xor(a1, 32);
  a2 += __shfl_xor(a2, 32); a3 += __shfl_xor(a3, 32);
  a4 += __shfl_xor(a4, 32); a5 += __shfl_xor(a5, 32);
  a6 += __shfl_xor(a6, 32); a7 += __shfl_xor(a7, 32);
  if (half == 0) {
    uint4 r;
    r.x = (unsigned)f2bf(a0) | ((unsigned)f2bf(a1) << 16);
    r.y = (unsigned)f2bf(a2) | ((unsigned)f2bf(a3) << 16);
    r.z = (unsigned)f2bf(a4) | ((unsigned)f2bf(a5) << 16);
    r.w = (unsigned)f2bf(a6) | ((unsigned)f2bf(a7) << 16);
    *(uint4*)(acc + (size_t)q * 1024 + head * CC + ch8) = r;
  }
}

// ================================================================= launch
extern "C" void kernel_launch(void* const* d_in, const int* in_sizes, int n_in,
                              void* d_out, int out_size, void* d_ws, size_t ws_size,
                              hipStream_t stream) {
  const float* S     = (const float*)d_in[0];
  const float* f0    = (const float*)d_in[1];
  const float* f1    = (const float*)d_in[2];
  const float* f2    = (const float*)d_in[3];
  const float* sim   = (const float*)d_in[4];
  const float* vw0   = (const float*)d_in[5];
  const float* vb0   = (const float*)d_in[6];
  const float* vw1   = (const float*)d_in[7];
  const float* vb1   = (const float*)d_in[8];
  const float* vw2   = (const float*)d_in[9];
  const float* vb2   = (const float*)d_in[10];
  const float* q_w   = (const float*)d_in[11];
  const float* q_b   = (const float*)d_in[12];
  const float* off_w = (const float*)d_in[13];
  const float* off_b = (const float*)d_in[14];
  const float* wgt_w = (const float*)d_in[15];
  const float* wgt_b = (const float*)d_in[16];
  const float* out_w = (const float*)d_in[17];
  const float* out_b = (const float*)d_in[18];
  const float* lnq_g = (const float*)d_in[19];
  const float* lnq_b = (const float*)d_in[20];
  const float* lno_g = (const float*)d_in[21];
  const float* lno_b = (const float*)d_in[22];
  const float* fc1_w = (const float*)d_in[23];
  const float* fc1_b = (const float*)d_in[24];
  const float* fc2_w = (const float*)d_in[25];
  const float* fc2_b = (const float*)d_in[26];

  char* p = (char*)d_ws;
  float* Z      = (float*)p; p += 8388608;
  float* offwgt = (float*)p; p += 4718592;
  float* bias144 = (float*)p; p += 1024;
  float* Pp     = (float*)p; p += 33554432;   // shared: Op (outA) then Fp (fc2A)
  float* Vp1    = (float*)p; p += 4194304;
  float* Vp2    = (float*)p; p += 2097152;
  unsigned short* Sbf   = (unsigned short*)p; p += 4194304;
  unsigned short* Qbf   = (unsigned short*)p; p += 4194304;   // alias Zbf
  unsigned short* accbf = (unsigned short*)p; p += 16777216;  // alias Xf*, hbf
  unsigned short* V0b   = (unsigned short*)p; p += 4194304;
  unsigned short* V1b   = (unsigned short*)p; p += 1048576;
  unsigned short* V2b   = (unsigned short*)p; p += 262144;
  unsigned short* q_wb   = (unsigned short*)p; p += 131072;
  unsigned short* owb    = (unsigned short*)p; p += 131072;
  unsigned short* vw0b   = (unsigned short*)p; p += 131072;
  unsigned short* vw1b   = (unsigned short*)p; p += 262144;
  unsigned short* vw2b   = (unsigned short*)p; p += 524288;
  unsigned short* out_wb = (unsigned short*)p; p += 524288;
  unsigned short* fc1_wb = (unsigned short*)p; p += 524288;
  unsigned short* fc2_wb = (unsigned short*)p; p += 524288;

  unsigned short* Xf0 = accbf;
  unsigned short* Xf1 = accbf + 2097152;
  unsigned short* Xf2 = accbf + 3145728;
  unsigned short* Zbf = Qbf;
  unsigned short* hbf = accbf;
  float* outp = (float*)d_out;

  prep_all_k<<<2944, 256, 0, stream>>>(S, f0, f1, f2, q_w, off_w, wgt_w,
      vw0, vw1, vw2, out_w, fc1_w, fc2_w, off_b, wgt_b,
      Sbf, Xf0, Xf1, Xf2, q_wb, owb, vw0b, vw1b, vw2b, out_wb,
      fc1_wb, fc2_wb, bias144);

  qv_k<<<704, 256, 0, stream>>>(Sbf, q_wb, q_b, lnq_g, lnq_b, Qbf,
      Xf0, Xf1, Xf2, vw0b, vw1b, vw2b, vb0, V0b, Vp1, Vp2);

  offv_k<<<896, 256, 0, stream>>>(Qbf, owb, bias144, offwgt,
      Vp1, Vp2, vb1, vb2, V1b, V2b);

  sample_k<<<8192, 256, 0, stream>>>(offwgt, sim, V0b, V1b, V2b, accbf);

  outA_k<<<dim3(256, 4), 256, 0, stream>>>(accbf, out_wb, Pp);

  outB_k<<<512, 256, 0, stream>>>(Pp, S, out_b, lno_g, lno_b, Z, Zbf);

  fc1_k<<<dim3(8, 128), 256, 0, stream>>>(Zbf, fc1_wb, fc1_b, hbf);

  fc2A_k<<<dim3(256, 4), 256, 0, stream>>>(hbf, fc2_wb, Pp);

  fc2B_k<<<128, 256, 0, stream>>>(Pp, Z, fc2_b, outp);
}

// Round 8
// 269.136 us; speedup vs baseline: 1.0645x; 1.0645x over previous
//
#include <hip/hip_runtime.h>
#include <hip/hip_bf16.h>
#include <math.h>

#define NQ 4096
#define CC 256

typedef __attribute__((ext_vector_type(8))) short bfrag;
typedef __attribute__((ext_vector_type(4))) float ffrag;

__device__ inline unsigned short f2bf(float x) {
  __hip_bfloat16 h = __float2bfloat16(x);
  return *reinterpret_cast<unsigned short*>(&h);
}

__device__ inline void gload16(const void* g, void* l) {
  __builtin_amdgcn_global_load_lds(
      (const __attribute__((address_space(1))) void*)g,
      (__attribute__((address_space(3))) void*)l, 16, 0, 0);
}

// ================================================================= prep mega
__device__ void tr64(const float* __restrict__ src,
                     unsigned short* __restrict__ dstb, int Cin, int P,
                     int p0, int c0, int b, float (*t)[73]) {
  int tid = threadIdx.x;
  int rx = tid & 15, ry = tid >> 4;
  const float* Sb = src + (size_t)b * Cin * P + p0 + rx * 4;
  #pragma unroll
  for (int i = 0; i < 4; i++) {
    int r = ry + i * 16;
    float4 v = *(const float4*)(Sb + (size_t)(c0 + r) * P);
    t[r][rx * 4 + 0] = v.x; t[r][rx * 4 + 1] = v.y;
    t[r][rx * 4 + 2] = v.z; t[r][rx * 4 + 3] = v.w;
  }
  __syncthreads();
  size_t ob = (size_t)b * P * Cin;
  #pragma unroll
  for (int i = 0; i < 4; i++) {
    int pr = ry + i * 16;
    float x0 = t[rx * 4 + 0][pr], x1 = t[rx * 4 + 1][pr];
    float x2 = t[rx * 4 + 2][pr], x3 = t[rx * 4 + 3][pr];
    size_t idx = ob + (size_t)(p0 + pr) * Cin + c0 + rx * 4;
    ushort4 u4;
    u4.x = f2bf(x0); u4.y = f2bf(x1); u4.z = f2bf(x2); u4.w = f2bf(x3);
    *(ushort4*)(dstb + idx) = u4;
  }
}

__global__ __launch_bounds__(256)
void prep_all_k(const float* S, const float* f0, const float* f1, const float* f2,
                const float* q_w, const float* off_w, const float* wgt_w,
                const float* vw0, const float* vw1, const float* vw2,
                const float* out_w, const float* fc1_w, const float* fc2_w,
                const float* off_b, const float* wgt_b,
                unsigned short* Sbf,
                unsigned short* Xf0, unsigned short* Xf1, unsigned short* Xf2,
                unsigned short* q_wb, unsigned short* owb,
                unsigned short* vw0b, unsigned short* vw1b, unsigned short* vw2b,
                unsigned short* out_wb, unsigned short* fc1_wb,
                unsigned short* fc2_wb, float* bias144) {
  __shared__ float t[64][73];
  int bid = blockIdx.x;
  if (bid < 512) {
    int l = bid;
    tr64(S, Sbf, 256, 4096, (l & 63) * 64, ((l >> 6) & 3) * 64, l >> 8, t);
  } else if (bid < 1024) {
    int l = bid - 512;
    tr64(f0, Xf0, 256, 4096, (l & 63) * 64, ((l >> 6) & 3) * 64, l >> 8, t);
  } else if (bid < 1280) {
    int l = bid - 1024;
    tr64(f1, Xf1, 512, 1024, (l & 15) * 64, ((l >> 4) & 7) * 64, l >> 7, t);
  } else if (bid < 1408) {
    int l = bid - 1280;
    tr64(f2, Xf2, 1024, 256, (l & 3) * 64, ((l >> 2) & 15) * 64, l >> 6, t);
  } else if (bid < 2688) {
    int i4 = (bid - 1408) * 256 + threadIdx.x;
    const float* src; unsigned short* dst;
    if (i4 < 16384)       { src = q_w;   dst = q_wb; }
    else if (i4 < 32768)  { i4 -= 16384;  src = vw0;   dst = vw0b; }
    else if (i4 < 65536)  { i4 -= 32768;  src = vw1;   dst = vw1b; }
    else if (i4 < 131072) { i4 -= 65536;  src = vw2;   dst = vw2b; }
    else if (i4 < 196608) { i4 -= 131072; src = out_w; dst = out_wb; }
    else if (i4 < 262144) { i4 -= 196608; src = fc1_w; dst = fc1_wb; }
    else                  { i4 -= 262144; src = fc2_w; dst = fc2_wb; }
    float4 v = ((const float4*)src)[i4];
    ushort4 u; u.x = f2bf(v.x); u.y = f2bf(v.y); u.z = f2bf(v.z); u.w = f2bf(v.w);
    ((ushort4*)dst)[i4] = u;
  } else {
    int e = (bid - 2688) * 256 + threadIdx.x;
    float v = (e < 24576) ? off_w[e] : (e < 36864 ? wgt_w[e - 24576] : 0.f);
    owb[e] = f2bf(v);
    if (e < 96) bias144[e] = off_b[e];
    else if (e < 144) bias144[e] = wgt_b[e - 96];
  }
}

// ================================================================= GEMM body
// BK=64 k-major LDS. EPI 0: fp32+bias  1: GELU->bf16  2: +bias+Zres transposed
// fp32 store  3: bf16+bias  4: fp32 no bias (partial)
template<int BM, int BN, int WM, int WN, int EPI>
__device__ __forceinline__ void gemm_body(
    const unsigned short* __restrict__ A, const unsigned short* __restrict__ B,
    const float* __restrict__ bias, float* __restrict__ outf,
    unsigned short* __restrict__ outb, int N, int Kloop, int lda, int ldb,
    int ldo, const float* __restrict__ Zres, float* __restrict__ outT,
    int m0, int n0, unsigned short* As, unsigned short* Bs) {
  constexpr int MI = BM / (WM * 16), NI = BN / (WN * 16);
  constexpr int TA = BM / 8, TB = BN / 8;
  constexpr int LBM = (BM == 32) ? 5 : (BM == 64) ? 6 : 7;
  constexpr int LBN = (BN == 64) ? 6 : (BN == 128) ? 7 : 8;
  int tid = threadIdx.x, wave = tid >> 6, lane = tid & 63;
  int quad = lane >> 4, l16 = lane & 15;
  int wm = wave / WN, wn = wave % WN;
  const int mbase = wm * (BM / WM), nbase = wn * (BN / WN);

  ffrag acc[MI][NI];
  #pragma unroll
  for (int i = 0; i < MI; i++)
    #pragma unroll
    for (int j = 0; j < NI; j++) acc[i][j] = (ffrag)0.f;

  for (int k0 = 0; k0 < Kloop; k0 += 64) {
    __syncthreads();
    for (int t = wave; t < TA + TB; t += 4) {
      if (t < TA) {
        int s = t * 64 + lane;
        int kc = s >> LBM, r = s & (BM - 1);
        gload16(A + (size_t)(m0 + r) * lda + k0 + kc * 8, (char*)As + t * 1024);
      } else {
        int s = (t - TA) * 64 + lane;
        int kc = s >> LBN, r = s & (BN - 1);
        gload16(B + (size_t)(n0 + r) * ldb + k0 + kc * 8, (char*)Bs + (t - TA) * 1024);
      }
    }
    __syncthreads();
    #pragma unroll
    for (int ks = 0; ks < 2; ks++) {
      bfrag af[MI], bf[NI];
      #pragma unroll
      for (int mi = 0; mi < MI; mi++)
        af[mi] = *(const bfrag*)(As + ((((ks * 4 + quad) << LBM) + mbase + mi * 16 + l16) << 3));
      #pragma unroll
      for (int ni = 0; ni < NI; ni++)
        bf[ni] = *(const bfrag*)(Bs + ((((ks * 4 + quad) << LBN) + nbase + ni * 16 + l16) << 3));
      #pragma unroll
      for (int mi = 0; mi < MI; mi++)
        #pragma unroll
        for (int ni = 0; ni < NI; ni++)
          acc[mi][ni] = __builtin_amdgcn_mfma_f32_16x16x32_bf16(
              af[mi], bf[ni], acc[mi][ni], 0, 0, 0);
    }
  }

  if (EPI == 2) {
    #pragma unroll
    for (int mi = 0; mi < MI; mi++) {
      int mrow = m0 + mbase + mi * 16 + quad * 4;
      int bb = mrow >> 12, q0 = mrow & (NQ - 1);
      #pragma unroll
      for (int ni = 0; ni < NI; ni++) {
        int n = n0 + nbase + ni * 16 + l16;
        float bv = bias[n];
        float4 v;
        v.x = acc[mi][ni][0] + bv + Zres[(size_t)(mrow + 0) * CC + n];
        v.y = acc[mi][ni][1] + bv + Zres[(size_t)(mrow + 1) * CC + n];
        v.z = acc[mi][ni][2] + bv + Zres[(size_t)(mrow + 2) * CC + n];
        v.w = acc[mi][ni][3] + bv + Zres[(size_t)(mrow + 3) * CC + n];
        *(float4*)(outT + ((size_t)(bb * CC + n)) * NQ + q0) = v;
      }
    }
  } else {
    #pragma unroll
    for (int mi = 0; mi < MI; mi++) {
      int mrow = m0 + mbase + mi * 16 + quad * 4;
      #pragma unroll
      for (int ni = 0; ni < NI; ni++) {
        int n = n0 + nbase + ni * 16 + l16;
        if (n < N) {
          float bv = (EPI == 4) ? 0.f : bias[n];
          #pragma unroll
          for (int r = 0; r < 4; r++) {
            float v = acc[mi][ni][r] + bv;
            if (EPI == 1) {
              v = 0.5f * v * (1.f + erff(v * 0.70710678118654752f));
              outb[(size_t)(mrow + r) * ldo + n] = f2bf(v);
            } else if (EPI == 3) {
              outb[(size_t)(mrow + r) * ldo + n] = f2bf(v);
            } else {
              outf[(size_t)(mrow + r) * ldo + n] = v;
            }
          }
        }
      }
    }
  }
}

// ================================================================= Q GEMM+LN
// BM=32, BN=256, BK=64 (proven config)
__device__ __forceinline__ void gemm_ln_q(
    const unsigned short* __restrict__ A, const unsigned short* __restrict__ B,
    const float* __restrict__ bias, unsigned short* __restrict__ outb,
    const float* __restrict__ g, const float* __restrict__ be,
    int m0, char* sm) {
  unsigned short* As = (unsigned short*)sm;
  unsigned short* Bs = (unsigned short*)(sm + 4096);
  float* L = (float*)sm;
  const int K = 256;

  int tid = threadIdx.x, wave = tid >> 6, lane = tid & 63;
  int quad = lane >> 4, l16 = lane & 15;

  ffrag acc[2][4];
  #pragma unroll
  for (int i = 0; i < 2; i++)
    #pragma unroll
    for (int j = 0; j < 4; j++) acc[i][j] = (ffrag)0.f;

  for (int k0 = 0; k0 < K; k0 += 64) {
    __syncthreads();
    for (int t = wave; t < 36; t += 4) {
      if (t < 4) {
        int s = t * 64 + lane;
        int kc = s >> 5, r = s & 31;
        gload16(A + (size_t)(m0 + r) * K + k0 + kc * 8, sm + t * 1024);
      } else {
        int s = (t - 4) * 64 + lane;
        int kc = s >> 8, r = s & 255;
        gload16(B + (size_t)r * K + k0 + kc * 8, sm + 4096 + (t - 4) * 1024);
      }
    }
    __syncthreads();
    #pragma unroll
    for (int ks = 0; ks < 2; ks++) {
      bfrag af[2], bf[4];
      #pragma unroll
      for (int mi = 0; mi < 2; mi++)
        af[mi] = *(const bfrag*)(As + ((((ks * 4 + quad) << 5) + mi * 16 + l16) << 3));
      #pragma unroll
      for (int ni = 0; ni < 4; ni++)
        bf[ni] = *(const bfrag*)(Bs + ((((ks * 4 + quad) << 8) + wave * 64 + ni * 16 + l16) << 3));
      #pragma unroll
      for (int mi = 0; mi < 2; mi++)
        #pragma unroll
        for (int ni = 0; ni < 4; ni++)
          acc[mi][ni] = __builtin_amdgcn_mfma_f32_16x16x32_bf16(
              af[mi], bf[ni], acc[mi][ni], 0, 0, 0);
    }
  }
  __syncthreads();

  #pragma unroll
  for (int mi = 0; mi < 2; mi++) {
    int row = mi * 16 + quad * 4;
    #pragma unroll
    for (int ni = 0; ni < 4; ni++) {
      int col = wave * 64 + ni * 16 + l16;
      float bv = bias[col];
      #pragma unroll
      for (int r = 0; r < 4; r++)
        L[(row + r) * 264 + col] = acc[mi][ni][r] + bv;
    }
  }
  __syncthreads();

  int row = tid >> 3, j = tid & 7;
  int seg = ((j + row) & 7) * 32;
  const float* Lr = L + row * 264 + seg;
  float s1 = 0.f, s2 = 0.f;
  #pragma unroll
  for (int i = 0; i < 8; i++) {
    float4 t4 = *(const float4*)(Lr + i * 4);
    s1 += t4.x + t4.y + t4.z + t4.w;
    s2 += t4.x * t4.x + t4.y * t4.y + t4.z * t4.z + t4.w * t4.w;
  }
  #pragma unroll
  for (int o = 1; o < 8; o <<= 1) {
    s1 += __shfl_xor(s1, o);
    s2 += __shfl_xor(s2, o);
  }
  float mu = s1 * (1.f / 256.f);
  float var = s2 * (1.f / 256.f) - mu * mu;
  float rs = rsqrtf(var + 1e-5f);
  int gm = m0 + row;
  #pragma unroll
  for (int i = 0; i < 8; i++) {
    int col = seg + i * 4;
    float4 t4 = *(const float4*)(Lr + i * 4);
    float4 gg = *(const float4*)(g + col);
    float4 bb4 = *(const float4*)(be + col);
    ushort4 ub;
    ub.x = f2bf((t4.x - mu) * rs * gg.x + bb4.x);
    ub.y = f2bf((t4.y - mu) * rs * gg.y + bb4.y);
    ub.z = f2bf((t4.z - mu) * rs * gg.z + bb4.z);
    ub.w = f2bf((t4.w - mu) * rs * gg.w + bb4.w);
    *(ushort4*)(outb + (size_t)gm * CC + col) = ub;
  }
}

// ================================================================= kernels
// qv: [0,256) Q-LN | [256,512) V0 | [512,640) V1 split2 | [640,704) V2 split4
__global__ __launch_bounds__(256)
void qv_k(const unsigned short* Sbf, const unsigned short* q_wb, const float* q_b,
          const float* lnq_g, const float* lnq_b, unsigned short* Qbf,
          const unsigned short* Xf0, const unsigned short* Xf1,
          const unsigned short* Xf2, const unsigned short* vw0b,
          const unsigned short* vw1b, const unsigned short* vw2b,
          const float* vb0, unsigned short* V0b, float* Vp1, float* Vp2) {
  __shared__ __attribute__((aligned(16))) char sm[36864];
  int bid = blockIdx.x;
  unsigned short* As = (unsigned short*)sm;
  unsigned short* Bs = (unsigned short*)(sm + 8192);
  if (bid < 256) {
    gemm_ln_q(Sbf, q_wb, q_b, Qbf, lnq_g, lnq_b, bid * 32, sm);
  } else if (bid < 512) {
    int t = bid - 256;
    gemm_body<64, 128, 2, 2, 3>(Xf0, vw0b, vb0, nullptr, V0b, 256, 256, 256, 256,
                                256, nullptr, nullptr, (t >> 1) * 64, (t & 1) * 128, As, Bs);
  } else if (bid < 640) {
    int l = bid - 512, ks = l >> 6, t = l & 63;
    gemm_body<64, 128, 2, 2, 4>(Xf1 + ks * 256, vw1b + ks * 256, nullptr,
                                Vp1 + (size_t)ks * 524288, nullptr, 256, 256, 512, 512,
                                256, nullptr, nullptr, (t >> 1) * 64, (t & 1) * 128, As, Bs);
  } else {
    int l = bid - 640, ks = l >> 4, t = l & 15;
    gemm_body<64, 128, 2, 2, 4>(Xf2 + ks * 256, vw2b + ks * 256, nullptr,
                                Vp2 + (size_t)ks * 131072, nullptr, 256, 256, 1024, 1024,
                                256, nullptr, nullptr, (t >> 1) * 64, (t & 1) * 128, As, Bs);
  }
}

// offv: [0,256) offwgt GEMM | [256,768) V1 reduce | [768,896) V2 reduce
__global__ __launch_bounds__(256)
void offv_k(const unsigned short* Qbf, const unsigned short* owb,
            const float* bias144, float* offwgt,
            const float* Vp1, const float* Vp2, const float* vb1,
            const float* vb2, unsigned short* V1b, unsigned short* V2b) {
  __shared__ __attribute__((aligned(16))) unsigned short As[4096];
  __shared__ __attribute__((aligned(16))) unsigned short Bs[8192];
  int bid = blockIdx.x;
  if (bid < 256) {
    gemm_body<64, 128, 2, 2, 0>(Qbf, owb, bias144, offwgt, nullptr, 144, 256, 256,
                                256, 144, nullptr, nullptr,
                                (bid >> 1) * 64, (bid & 1) * 128, As, Bs);
  } else if (bid < 768) {
    int e4 = (bid - 256) * 256 + threadIdx.x;
    const float4* P = (const float4*)Vp1;
    float4 a = P[e4], b = P[e4 + 131072];
    float4 bb = *(const float4*)(vb1 + ((e4 << 2) & 255));
    ushort4 u;
    u.x = f2bf(a.x + b.x + bb.x); u.y = f2bf(a.y + b.y + bb.y);
    u.z = f2bf(a.z + b.z + bb.z); u.w = f2bf(a.w + b.w + bb.w);
    ((ushort4*)V1b)[e4] = u;
  } else {
    int e4 = (bid - 768) * 256 + threadIdx.x;
    const float4* P = (const float4*)Vp2;
    float4 a = P[e4], b = P[e4 + 32768], c = P[e4 + 65536], d = P[e4 + 98304];
    float4 bb = *(const float4*)(vb2 + ((e4 << 2) & 255));
    ushort4 u;
    u.x = f2bf(a.x + b.x + c.x + d.x + bb.x);
    u.y = f2bf(a.y + b.y + c.y + d.y + bb.y);
    u.z = f2bf(a.z + b.z + c.z + d.z + bb.z);
    u.w = f2bf(a.w + b.w + c.w + d.w + bb.w);
    ((ushort4*)V2b)[e4] = u;
  }
}

// outA: split-K=4 GEMM acc@out_w -> fp32 partials [4][8192][256]
__global__ __launch_bounds__(256)
void outA_k(const unsigned short* accbf, const unsigned short* out_wb, float* Op) {
  __shared__ __attribute__((aligned(16))) char sm[36864];
  int ks = blockIdx.y;
  gemm_body<32, 256, 1, 4, 4>(accbf + ks * 256, out_wb + ks * 256, nullptr,
                              Op + (size_t)ks * 2097152, nullptr, 256, 256, 1024,
                              1024, 256, nullptr, nullptr, blockIdx.x * 32, 0,
                              (unsigned short*)sm, (unsigned short*)(sm + 4096));
}

// outB: reduce 4 partials + bias + S residual + LN -> Zf fp32, Zbf bf16
__global__ __launch_bounds__(256)
void outB_k(const float* __restrict__ Op, const float* __restrict__ S,
            const float* __restrict__ out_b, const float* __restrict__ g,
            const float* __restrict__ be, float* __restrict__ Zf,
            unsigned short* __restrict__ Zbf) {
  __shared__ float Ls[16][264];
  int q0 = blockIdx.x * 16;
  int b = q0 >> 12, qq = q0 & (NQ - 1);
  int t = threadIdx.x;
  {
    int cs = t >> 2, j = (t & 3) * 4;
    #pragma unroll
    for (int c0 = 0; c0 < 256; c0 += 64) {
      float4 sv = *(const float4*)(S + (((size_t)(b * 256 + c0 + cs)) << 12) + qq + j);
      Ls[j + 0][c0 + cs] = sv.x; Ls[j + 1][c0 + cs] = sv.y;
      Ls[j + 2][c0 + cs] = sv.z; Ls[j + 3][c0 + cs] = sv.w;
    }
  }
  __syncthreads();
  int c = t;
  float bv = out_b[c];
  float val[16];
  #pragma unroll
  for (int r = 0; r < 16; r++) {
    size_t idx = (size_t)(q0 + r) * 256 + c;
    val[r] = Op[idx] + Op[idx + 2097152] + Op[idx + 4194304] + Op[idx + 6291456]
           + bv + Ls[r][c];
  }
  __syncthreads();
  #pragma unroll
  for (int r = 0; r < 16; r++) Ls[r][c] = val[r];
  __syncthreads();
  int row = t >> 4, lg = t & 15;
  const float* Lr = &Ls[row][lg * 16];
  float s1 = 0.f, s2 = 0.f;
  #pragma unroll
  for (int i = 0; i < 4; i++) {
    float4 t4 = *(const float4*)(Lr + i * 4);
    s1 += t4.x + t4.y + t4.z + t4.w;
    s2 += t4.x * t4.x + t4.y * t4.y + t4.z * t4.z + t4.w * t4.w;
  }
  #pragma unroll
  for (int o = 1; o < 16; o <<= 1) {
    s1 += __shfl_xor(s1, o);
    s2 += __shfl_xor(s2, o);
  }
  float mu = s1 * (1.f / 256.f);
  float var = s2 * (1.f / 256.f) - mu * mu;
  float rs = rsqrtf(var + 1e-5f);
  int gm = q0 + row;
  #pragma unroll
  for (int i = 0; i < 4; i++) {
    int col = lg * 16 + i * 4;
    float4 t4 = *(const float4*)(Lr + i * 4);
    float4 gg = *(const float4*)(g + col);
    float4 bb4 = *(const float4*)(be + col);
    float4 y;
    y.x = (t4.x - mu) * rs * gg.x + bb4.x;
    y.y = (t4.y - mu) * rs * gg.y + bb4.y;
    y.z = (t4.z - mu) * rs * gg.z + bb4.z;
    y.w = (t4.w - mu) * rs * gg.w + bb4.w;
    *(float4*)(Zf + (size_t)gm * CC + col) = y;
    ushort4 ub;
    ub.x = f2bf(y.x); ub.y = f2bf(y.y); ub.z = f2bf(y.z); ub.w = f2bf(y.w);
    *(ushort4*)(Zbf + (size_t)gm * CC + col) = ub;
  }
}

__global__ __launch_bounds__(256)
void fc1_k(const unsigned short* Zbf, const unsigned short* fc1_wb,
           const float* fc1_b, unsigned short* hbf) {
  __shared__ __attribute__((aligned(16))) unsigned short As[4096];
  __shared__ __attribute__((aligned(16))) unsigned short Bs[8192];
  gemm_body<64, 128, 2, 2, 1>(Zbf, fc1_wb, fc1_b, nullptr, hbf, 1024, 256, 256,
                              256, 1024, nullptr, nullptr,
                              blockIdx.y * 64, blockIdx.x * 128, As, Bs);
}

// fc2: fused full-K=1024, 64x64 tile (round-4 proven config), EPI=2
__global__ __launch_bounds__(256)
void fc2_k(const unsigned short* hbf, const unsigned short* fc2_wb,
           const float* fc2_b, const float* Z, float* outp) {
  __shared__ __attribute__((aligned(16))) unsigned short As[4096];
  __shared__ __attribute__((aligned(16))) unsigned short Bs[4096];
  gemm_body<64, 64, 2, 2, 2>(hbf, fc2_wb, fc2_b, nullptr, nullptr, 256, 1024,
                             1024, 1024, 256, Z, outp,
                             blockIdx.y * 64, blockIdx.x * 64, As, Bs);
}

// ================================================================= sampling
__global__ __launch_bounds__(256)
void sample_k(const float* __restrict__ ow, const float* __restrict__ sim,
              const unsigned short* __restrict__ V0, const unsigned short* __restrict__ V1,
              const unsigned short* __restrict__ V2, unsigned short* __restrict__ acc) {
  int bn = blockIdx.x;
  int q = ((bn & 7) << 10) | (bn >> 3);
  int b = q >> 12, n = q & (NQ - 1);
  int tid = threadIdx.x, head = tid >> 6, lane = tid & 63;
  int half = lane >> 5, l32 = lane & 31;

  __shared__ float s_w[48];
  __shared__ int   s_xy[48][2];
  __shared__ float s_f[48][2];
  __shared__ uint2 s_ow[192];

  if (tid < 48) {
    int hh = tid / 12, pt = tid % 12, l = pt >> 2, mm = pt & 3;
    int oidx = (hh * 3 + l) * 4 + mm;
    float offx = ow[(size_t)q * 144 + oidx * 2 + 0];
    float offy = ow[(size_t)q * 144 + oidx * 2 + 1];
    float refx = ((n & 63) + 0.5f) * (1.f / 64.f);
    float refy = ((n >> 6) + 0.5f) * (1.f / 64.f);
    float gx = tanhf((refx + offx) * 2.f - 1.f);
    float gy = tanhf((refy + offy) * 2.f - 1.f);
    gx = fminf(1.f, fmaxf(-1.f, gx));
    gy = fminf(1.f, fmaxf(-1.f, gy));
    int Wl = 64 >> l;
    float x = (gx + 1.f) * 0.5f * (float)(Wl - 1);
    float y = (gy + 1.f) * 0.5f * (float)(Wl - 1);
    float x0 = floorf(x), y0 = floorf(y);
    s_xy[tid][0] = (int)x0;
    s_xy[tid][1] = (int)y0;
    s_f[tid][0] = x - x0;
    s_f[tid][1] = y - y0;
    s_w[tid] = ow[(size_t)q * 144 + 96 + oidx] * (sim[q] + 0.001f);
  }
  __syncthreads();
  if (tid < 4) {
    float mx = -1e30f;
    #pragma unroll
    for (int i = 0; i < 12; i++) mx = fmaxf(mx, s_w[tid * 12 + i]);
    float e[12], ssum = 0.f;
    #pragma unroll
    for (int i = 0; i < 12; i++) { e[i] = expf(s_w[tid * 12 + i] - mx); ssum += e[i]; }
    float inv = 1.f / ssum;
    #pragma unroll
    for (int i = 0; i < 12; i++) s_w[tid * 12 + i] = e[i] * inv;
  }
  __syncthreads();
  if (tid < 192) {
    int s = tid >> 2, tap = tid & 3;
    int l = (s % 12) >> 2;
    int Wl = 64 >> l;
    int X = s_xy[s][0] + (tap & 1), Y = s_xy[s][1] + (tap >> 1);
    bool valid = (X >= 0 && X < Wl && Y >= 0 && Y < Wl);
    float wx = (tap & 1) ? s_f[s][0] : 1.f - s_f[s][0];
    float wy = (tap >> 1) ? s_f[s][1] : 1.f - s_f[s][1];
    float twt = valid ? s_w[s] * wx * wy : 0.f;
    int Xc = min(max(X, 0), Wl - 1), Yc = min(max(Y, 0), Wl - 1);
    s_ow[tid].x = (unsigned)((Yc * Wl + Xc) << 8);
    s_ow[tid].y = __float_as_uint(twt);
  }
  __syncthreads();

  const unsigned short* B0 = V0 + (size_t)b * 4096 * CC;
  const unsigned short* B1 = V1 + (size_t)b * 1024 * CC;
  const unsigned short* B2 = V2 + (size_t)b * 256 * CC;
  int ch8 = l32 * 8;
  float a0 = 0.f, a1 = 0.f, a2 = 0.f, a3 = 0.f;
  float a4 = 0.f, a5 = 0.f, a6 = 0.f, a7 = 0.f;
  #pragma unroll
  for (int it = 0; it < 24; it++) {
    const unsigned short* base = (it < 8) ? B0 : (it < 16) ? B1 : B2;
    uint2 owv = s_ow[head * 48 + it * 2 + half];
    float w = __uint_as_float(owv.y);
    const uint4 u = *(const uint4*)(base + owv.x + ch8);
    a0 = fmaf(w, __uint_as_float(u.x << 16), a0);
    a1 = fmaf(w, __uint_as_float(u.x & 0xffff0000u), a1);
    a2 = fmaf(w, __uint_as_float(u.y << 16), a2);
    a3 = fmaf(w, __uint_as_float(u.y & 0xffff0000u), a3);
    a4 = fmaf(w, __uint_as_float(u.z << 16), a4);
    a5 = fmaf(w, __uint_as_float(u.z & 0xffff0000u), a5);
    a6 = fmaf(w, __uint_as_float(u.w << 16), a6);
    a7 = fmaf(w, __uint_as_float(u.w & 0xffff0000u), a7);
  }
  a0 += __shfl_xor(a0, 32); a1 += __shfl_xor(a1, 32);
  a2 += __shfl_xor(a2, 32); a3 += __shfl_xor(a3, 32);
  a4 += __shfl_xor(a4, 32); a5 += __shfl_xor(a5, 32);
  a6 += __shfl_xor(a6, 32); a7 += __shfl_xor(a7, 32);
  if (half == 0) {
    uint4 r;
    r.x = (unsigned)f2bf(a0) | ((unsigned)f2bf(a1) << 16);
    r.y = (unsigned)f2bf(a2) | ((unsigned)f2bf(a3) << 16);
    r.z = (unsigned)f2bf(a4) | ((unsigned)f2bf(a5) << 16);
    r.w = (unsigned)f2bf(a6) | ((unsigned)f2bf(a7) << 16);
    *(uint4*)(acc + (size_t)q * 1024 + head * CC + ch8) = r;
  }
}

// ================================================================= launch
extern "C" void kernel_launch(void* const* d_in, const int* in_sizes, int n_in,
                              void* d_out, int out_size, void* d_ws, size_t ws_size,
                              hipStream_t stream) {
  const float* S     = (const float*)d_in[0];
  const float* f0    = (const float*)d_in[1];
  const float* f1    = (const float*)d_in[2];
  const float* f2    = (const float*)d_in[3];
  const float* sim   = (const float*)d_in[4];
  const float* vw0   = (const float*)d_in[5];
  const float* vb0   = (const float*)d_in[6];
  const float* vw1   = (const float*)d_in[7];
  const float* vb1   = (const float*)d_in[8];
  const float* vw2   = (const float*)d_in[9];
  const float* vb2   = (const float*)d_in[10];
  const float* q_w   = (const float*)d_in[11];
  const float* q_b   = (const float*)d_in[12];
  const float* off_w = (const float*)d_in[13];
  const float* off_b = (const float*)d_in[14];
  const float* wgt_w = (const float*)d_in[15];
  const float* wgt_b = (const float*)d_in[16];
  const float* out_w = (const float*)d_in[17];
  const float* out_b = (const float*)d_in[18];
  const float* lnq_g = (const float*)d_in[19];
  const float* lnq_b = (const float*)d_in[20];
  const float* lno_g = (const float*)d_in[21];
  const float* lno_b = (const float*)d_in[22];
  const float* fc1_w = (const float*)d_in[23];
  const float* fc1_b = (const float*)d_in[24];
  const float* fc2_w = (const float*)d_in[25];
  const float* fc2_b = (const float*)d_in[26];

  char* p = (char*)d_ws;
  float* Z      = (float*)p; p += 8388608;
  float* offwgt = (float*)p; p += 4718592;
  float* bias144 = (float*)p; p += 1024;
  float* Pp     = (float*)p; p += 33554432;   // outA partials
  float* Vp1    = (float*)p; p += 4194304;
  float* Vp2    = (float*)p; p += 2097152;
  unsigned short* Sbf   = (unsigned short*)p; p += 4194304;
  unsigned short* Qbf   = (unsigned short*)p; p += 4194304;   // alias Zbf
  unsigned short* accbf = (unsigned short*)p; p += 16777216;  // alias Xf*, hbf
  unsigned short* V0b   = (unsigned short*)p; p += 4194304;
  unsigned short* V1b   = (unsigned short*)p; p += 1048576;
  unsigned short* V2b   = (unsigned short*)p; p += 262144;
  unsigned short* q_wb   = (unsigned short*)p; p += 131072;
  unsigned short* owb    = (unsigned short*)p; p += 131072;
  unsigned short* vw0b   = (unsigned short*)p; p += 131072;
  unsigned short* vw1b   = (unsigned short*)p; p += 262144;
  unsigned short* vw2b   = (unsigned short*)p; p += 524288;
  unsigned short* out_wb = (unsigned short*)p; p += 524288;
  unsigned short* fc1_wb = (unsigned short*)p; p += 524288;
  unsigned short* fc2_wb = (unsigned short*)p; p += 524288;

  unsigned short* Xf0 = accbf;
  unsigned short* Xf1 = accbf + 2097152;
  unsigned short* Xf2 = accbf + 3145728;
  unsigned short* Zbf = Qbf;
  unsigned short* hbf = accbf;
  float* outp = (float*)d_out;

  prep_all_k<<<2944, 256, 0, stream>>>(S, f0, f1, f2, q_w, off_w, wgt_w,
      vw0, vw1, vw2, out_w, fc1_w, fc2_w, off_b, wgt_b,
      Sbf, Xf0, Xf1, Xf2, q_wb, owb, vw0b, vw1b, vw2b, out_wb,
      fc1_wb, fc2_wb, bias144);

  qv_k<<<704, 256, 0, stream>>>(Sbf, q_wb, q_b, lnq_g, lnq_b, Qbf,
      Xf0, Xf1, Xf2, vw0b, vw1b, vw2b, vb0, V0b, Vp1, Vp2);

  offv_k<<<896, 256, 0, stream>>>(Qbf, owb, bias144, offwgt,
      Vp1, Vp2, vb1, vb2, V1b, V2b);

  sample_k<<<8192, 256, 0, stream>>>(offwgt, sim, V0b, V1b, V2b, accbf);

  outA_k<<<dim3(256, 4), 256, 0, stream>>>(accbf, out_wb, Pp);

  outB_k<<<512, 256, 0, stream>>>(Pp, S, out_b, lno_g, lno_b, Z, Zbf);

  fc1_k<<<dim3(8, 128), 256, 0, stream>>>(Zbf, fc1_wb, fc1_b, hbf);

  fc2_k<<<dim3(4, 128), 256, 0, stream>>>(hbf, fc2_wb, fc2_b, Z, outp);
}

// Round 9
// 263.757 us; speedup vs baseline: 1.0862x; 1.0204x over previous
//
#include <hip/hip_runtime.h>
#include <hip/hip_bf16.h>
#include <math.h>

#define NQ 4096
#define CC 256

typedef __attribute__((ext_vector_type(8))) short bfrag;
typedef __attribute__((ext_vector_type(4))) float ffrag;

__device__ inline unsigned short f2bf(float x) {
  __hip_bfloat16 h = __float2bfloat16(x);
  return *reinterpret_cast<unsigned short*>(&h);
}

__device__ inline float bf2f(unsigned short u) {
  return __uint_as_float(((unsigned)u) << 16);
}

__device__ inline void gload16(const void* g, void* l) {
  __builtin_amdgcn_global_load_lds(
      (const __attribute__((address_space(1))) void*)g,
      (__attribute__((address_space(3))) void*)l, 16, 0, 0);
}

// ================================================================= prep mega
__device__ void tr64(const float* __restrict__ src,
                     unsigned short* __restrict__ dstb, int Cin, int P,
                     int p0, int c0, int b, float (*t)[73]) {
  int tid = threadIdx.x;
  int rx = tid & 15, ry = tid >> 4;
  const float* Sb = src + (size_t)b * Cin * P + p0 + rx * 4;
  #pragma unroll
  for (int i = 0; i < 4; i++) {
    int r = ry + i * 16;
    float4 v = *(const float4*)(Sb + (size_t)(c0 + r) * P);
    t[r][rx * 4 + 0] = v.x; t[r][rx * 4 + 1] = v.y;
    t[r][rx * 4 + 2] = v.z; t[r][rx * 4 + 3] = v.w;
  }
  __syncthreads();
  size_t ob = (size_t)b * P * Cin;
  #pragma unroll
  for (int i = 0; i < 4; i++) {
    int pr = ry + i * 16;
    float x0 = t[rx * 4 + 0][pr], x1 = t[rx * 4 + 1][pr];
    float x2 = t[rx * 4 + 2][pr], x3 = t[rx * 4 + 3][pr];
    size_t idx = ob + (size_t)(p0 + pr) * Cin + c0 + rx * 4;
    ushort4 u4;
    u4.x = f2bf(x0); u4.y = f2bf(x1); u4.z = f2bf(x2); u4.w = f2bf(x3);
    *(ushort4*)(dstb + idx) = u4;
  }
}

__global__ __launch_bounds__(256)
void prep_all_k(const float* S, const float* f0, const float* f1, const float* f2,
                const float* q_w, const float* off_w, const float* wgt_w,
                const float* vw0, const float* vw1, const float* vw2,
                const float* out_w, const float* fc1_w, const float* fc2_w,
                const float* off_b, const float* wgt_b,
                unsigned short* Sbf,
                unsigned short* Xf0, unsigned short* Xf1, unsigned short* Xf2,
                unsigned short* q_wb, unsigned short* owb,
                unsigned short* vw0b, unsigned short* vw1b, unsigned short* vw2b,
                unsigned short* out_wb, unsigned short* fc1_wb,
                unsigned short* fc2_wb, float* bias144) {
  __shared__ float t[64][73];
  int bid = blockIdx.x;
  if (bid < 512) {
    int l = bid;
    tr64(S, Sbf, 256, 4096, (l & 63) * 64, ((l >> 6) & 3) * 64, l >> 8, t);
  } else if (bid < 1024) {
    int l = bid - 512;
    tr64(f0, Xf0, 256, 4096, (l & 63) * 64, ((l >> 6) & 3) * 64, l >> 8, t);
  } else if (bid < 1280) {
    int l = bid - 1024;
    tr64(f1, Xf1, 512, 1024, (l & 15) * 64, ((l >> 4) & 7) * 64, l >> 7, t);
  } else if (bid < 1408) {
    int l = bid - 1280;
    tr64(f2, Xf2, 1024, 256, (l & 3) * 64, ((l >> 2) & 15) * 64, l >> 6, t);
  } else if (bid < 2688) {
    int i4 = (bid - 1408) * 256 + threadIdx.x;
    const float* src; unsigned short* dst;
    if (i4 < 16384)       { src = q_w;   dst = q_wb; }
    else if (i4 < 32768)  { i4 -= 16384;  src = vw0;   dst = vw0b; }
    else if (i4 < 65536)  { i4 -= 32768;  src = vw1;   dst = vw1b; }
    else if (i4 < 131072) { i4 -= 65536;  src = vw2;   dst = vw2b; }
    else if (i4 < 196608) { i4 -= 131072; src = out_w; dst = out_wb; }
    else if (i4 < 262144) { i4 -= 196608; src = fc1_w; dst = fc1_wb; }
    else                  { i4 -= 262144; src = fc2_w; dst = fc2_wb; }
    float4 v = ((const float4*)src)[i4];
    ushort4 u; u.x = f2bf(v.x); u.y = f2bf(v.y); u.z = f2bf(v.z); u.w = f2bf(v.w);
    ((ushort4*)dst)[i4] = u;
  } else {
    int e = (bid - 2688) * 256 + threadIdx.x;
    float v = (e < 24576) ? off_w[e] : (e < 36864 ? wgt_w[e - 24576] : 0.f);
    owb[e] = f2bf(v);
    if (e < 96) bias144[e] = off_b[e];
    else if (e < 144) bias144[e] = wgt_b[e - 96];
  }
}

// ================================================================= GEMM body
// BK=64 k-major LDS. EPI 0: fp32+bias  1: GELU->bf16  2: +bias+bf16 Zres,
// transposed fp32 store  3: bf16+bias  4: fp32 no bias (partial)
template<int BM, int BN, int WM, int WN, int EPI>
__device__ __forceinline__ void gemm_body(
    const unsigned short* __restrict__ A, const unsigned short* __restrict__ B,
    const float* __restrict__ bias, float* __restrict__ outf,
    unsigned short* __restrict__ outb, int N, int Kloop, int lda, int ldb,
    int ldo, const unsigned short* __restrict__ Zres, float* __restrict__ outT,
    int m0, int n0, unsigned short* As, unsigned short* Bs) {
  constexpr int MI = BM / (WM * 16), NI = BN / (WN * 16);
  constexpr int TA = BM / 8, TB = BN / 8;
  constexpr int LBM = (BM == 32) ? 5 : (BM == 64) ? 6 : 7;
  constexpr int LBN = (BN == 64) ? 6 : (BN == 128) ? 7 : 8;
  int tid = threadIdx.x, wave = tid >> 6, lane = tid & 63;
  int quad = lane >> 4, l16 = lane & 15;
  int wm = wave / WN, wn = wave % WN;
  const int mbase = wm * (BM / WM), nbase = wn * (BN / WN);

  ffrag acc[MI][NI];
  #pragma unroll
  for (int i = 0; i < MI; i++)
    #pragma unroll
    for (int j = 0; j < NI; j++) acc[i][j] = (ffrag)0.f;

  for (int k0 = 0; k0 < Kloop; k0 += 64) {
    __syncthreads();
    for (int t = wave; t < TA + TB; t += 4) {
      if (t < TA) {
        int s = t * 64 + lane;
        int kc = s >> LBM, r = s & (BM - 1);
        gload16(A + (size_t)(m0 + r) * lda + k0 + kc * 8, (char*)As + t * 1024);
      } else {
        int s = (t - TA) * 64 + lane;
        int kc = s >> LBN, r = s & (BN - 1);
        gload16(B + (size_t)(n0 + r) * ldb + k0 + kc * 8, (char*)Bs + (t - TA) * 1024);
      }
    }
    __syncthreads();
    #pragma unroll
    for (int ks = 0; ks < 2; ks++) {
      bfrag af[MI], bf[NI];
      #pragma unroll
      for (int mi = 0; mi < MI; mi++)
        af[mi] = *(const bfrag*)(As + ((((ks * 4 + quad) << LBM) + mbase + mi * 16 + l16) << 3));
      #pragma unroll
      for (int ni = 0; ni < NI; ni++)
        bf[ni] = *(const bfrag*)(Bs + ((((ks * 4 + quad) << LBN) + nbase + ni * 16 + l16) << 3));
      #pragma unroll
      for (int mi = 0; mi < MI; mi++)
        #pragma unroll
        for (int ni = 0; ni < NI; ni++)
          acc[mi][ni] = __builtin_amdgcn_mfma_f32_16x16x32_bf16(
              af[mi], bf[ni], acc[mi][ni], 0, 0, 0);
    }
  }

  if (EPI == 2) {
    #pragma unroll
    for (int mi = 0; mi < MI; mi++) {
      int mrow = m0 + mbase + mi * 16 + quad * 4;
      int bb = mrow >> 12, q0 = mrow & (NQ - 1);
      #pragma unroll
      for (int ni = 0; ni < NI; ni++) {
        int n = n0 + nbase + ni * 16 + l16;
        float bv = bias[n];
        float4 v;
        v.x = acc[mi][ni][0] + bv + bf2f(Zres[(size_t)(mrow + 0) * CC + n]);
        v.y = acc[mi][ni][1] + bv + bf2f(Zres[(size_t)(mrow + 1) * CC + n]);
        v.z = acc[mi][ni][2] + bv + bf2f(Zres[(size_t)(mrow + 2) * CC + n]);
        v.w = acc[mi][ni][3] + bv + bf2f(Zres[(size_t)(mrow + 3) * CC + n]);
        *(float4*)(outT + ((size_t)(bb * CC + n)) * NQ + q0) = v;
      }
    }
  } else {
    #pragma unroll
    for (int mi = 0; mi < MI; mi++) {
      int mrow = m0 + mbase + mi * 16 + quad * 4;
      #pragma unroll
      for (int ni = 0; ni < NI; ni++) {
        int n = n0 + nbase + ni * 16 + l16;
        if (n < N) {
          float bv = (EPI == 4) ? 0.f : bias[n];
          #pragma unroll
          for (int r = 0; r < 4; r++) {
            float v = acc[mi][ni][r] + bv;
            if (EPI == 1) {
              v = 0.5f * v * (1.f + erff(v * 0.70710678118654752f));
              outb[(size_t)(mrow + r) * ldo + n] = f2bf(v);
            } else if (EPI == 3) {
              outb[(size_t)(mrow + r) * ldo + n] = f2bf(v);
            } else {
              outf[(size_t)(mrow + r) * ldo + n] = v;
            }
          }
        }
      }
    }
  }
}

// ================================================================= Q GEMM+LN
// BM=32, BN=256, BK=64 (proven config)
__device__ __forceinline__ void gemm_ln_q(
    const unsigned short* __restrict__ A, const unsigned short* __restrict__ B,
    const float* __restrict__ bias, unsigned short* __restrict__ outb,
    const float* __restrict__ g, const float* __restrict__ be,
    int m0, char* sm) {
  unsigned short* As = (unsigned short*)sm;
  unsigned short* Bs = (unsigned short*)(sm + 4096);
  float* L = (float*)sm;
  const int K = 256;

  int tid = threadIdx.x, wave = tid >> 6, lane = tid & 63;
  int quad = lane >> 4, l16 = lane & 15;

  ffrag acc[2][4];
  #pragma unroll
  for (int i = 0; i < 2; i++)
    #pragma unroll
    for (int j = 0; j < 4; j++) acc[i][j] = (ffrag)0.f;

  for (int k0 = 0; k0 < K; k0 += 64) {
    __syncthreads();
    for (int t = wave; t < 36; t += 4) {
      if (t < 4) {
        int s = t * 64 + lane;
        int kc = s >> 5, r = s & 31;
        gload16(A + (size_t)(m0 + r) * K + k0 + kc * 8, sm + t * 1024);
      } else {
        int s = (t - 4) * 64 + lane;
        int kc = s >> 8, r = s & 255;
        gload16(B + (size_t)r * K + k0 + kc * 8, sm + 4096 + (t - 4) * 1024);
      }
    }
    __syncthreads();
    #pragma unroll
    for (int ks = 0; ks < 2; ks++) {
      bfrag af[2], bf[4];
      #pragma unroll
      for (int mi = 0; mi < 2; mi++)
        af[mi] = *(const bfrag*)(As + ((((ks * 4 + quad) << 5) + mi * 16 + l16) << 3));
      #pragma unroll
      for (int ni = 0; ni < 4; ni++)
        bf[ni] = *(const bfrag*)(Bs + ((((ks * 4 + quad) << 8) + wave * 64 + ni * 16 + l16) << 3));
      #pragma unroll
      for (int mi = 0; mi < 2; mi++)
        #pragma unroll
        for (int ni = 0; ni < 4; ni++)
          acc[mi][ni] = __builtin_amdgcn_mfma_f32_16x16x32_bf16(
              af[mi], bf[ni], acc[mi][ni], 0, 0, 0);
    }
  }
  __syncthreads();

  #pragma unroll
  for (int mi = 0; mi < 2; mi++) {
    int row = mi * 16 + quad * 4;
    #pragma unroll
    for (int ni = 0; ni < 4; ni++) {
      int col = wave * 64 + ni * 16 + l16;
      float bv = bias[col];
      #pragma unroll
      for (int r = 0; r < 4; r++)
        L[(row + r) * 264 + col] = acc[mi][ni][r] + bv;
    }
  }
  __syncthreads();

  int row = tid >> 3, j = tid & 7;
  int seg = ((j + row) & 7) * 32;
  const float* Lr = L + row * 264 + seg;
  float s1 = 0.f, s2 = 0.f;
  #pragma unroll
  for (int i = 0; i < 8; i++) {
    float4 t4 = *(const float4*)(Lr + i * 4);
    s1 += t4.x + t4.y + t4.z + t4.w;
    s2 += t4.x * t4.x + t4.y * t4.y + t4.z * t4.z + t4.w * t4.w;
  }
  #pragma unroll
  for (int o = 1; o < 8; o <<= 1) {
    s1 += __shfl_xor(s1, o);
    s2 += __shfl_xor(s2, o);
  }
  float mu = s1 * (1.f / 256.f);
  float var = s2 * (1.f / 256.f) - mu * mu;
  float rs = rsqrtf(var + 1e-5f);
  int gm = m0 + row;
  #pragma unroll
  for (int i = 0; i < 8; i++) {
    int col = seg + i * 4;
    float4 t4 = *(const float4*)(Lr + i * 4);
    float4 gg = *(const float4*)(g + col);
    float4 bb4 = *(const float4*)(be + col);
    ushort4 ub;
    ub.x = f2bf((t4.x - mu) * rs * gg.x + bb4.x);
    ub.y = f2bf((t4.y - mu) * rs * gg.y + bb4.y);
    ub.z = f2bf((t4.z - mu) * rs * gg.z + bb4.z);
    ub.w = f2bf((t4.w - mu) * rs * gg.w + bb4.w);
    *(ushort4*)(outb + (size_t)gm * CC + col) = ub;
  }
}

// ================================================================= kernels
// qv: [0,256) Q-LN | [256,512) V0 | [512,640) V1 split2 | [640,704) V2 split4
__global__ __launch_bounds__(256)
void qv_k(const unsigned short* Sbf, const unsigned short* q_wb, const float* q_b,
          const float* lnq_g, const float* lnq_b, unsigned short* Qbf,
          const unsigned short* Xf0, const unsigned short* Xf1,
          const unsigned short* Xf2, const unsigned short* vw0b,
          const unsigned short* vw1b, const unsigned short* vw2b,
          const float* vb0, unsigned short* V0b, float* Vp1, float* Vp2) {
  __shared__ __attribute__((aligned(16))) char sm[36864];
  int bid = blockIdx.x;
  unsigned short* As = (unsigned short*)sm;
  unsigned short* Bs = (unsigned short*)(sm + 8192);
  if (bid < 256) {
    gemm_ln_q(Sbf, q_wb, q_b, Qbf, lnq_g, lnq_b, bid * 32, sm);
  } else if (bid < 512) {
    int t = bid - 256;
    gemm_body<64, 128, 2, 2, 3>(Xf0, vw0b, vb0, nullptr, V0b, 256, 256, 256, 256,
                                256, nullptr, nullptr, (t >> 1) * 64, (t & 1) * 128, As, Bs);
  } else if (bid < 640) {
    int l = bid - 512, ks = l >> 6, t = l & 63;
    gemm_body<64, 128, 2, 2, 4>(Xf1 + ks * 256, vw1b + ks * 256, nullptr,
                                Vp1 + (size_t)ks * 524288, nullptr, 256, 256, 512, 512,
                                256, nullptr, nullptr, (t >> 1) * 64, (t & 1) * 128, As, Bs);
  } else {
    int l = bid - 640, ks = l >> 4, t = l & 15;
    gemm_body<64, 128, 2, 2, 4>(Xf2 + ks * 256, vw2b + ks * 256, nullptr,
                                Vp2 + (size_t)ks * 131072, nullptr, 256, 256, 1024, 1024,
                                256, nullptr, nullptr, (t >> 1) * 64, (t & 1) * 128, As, Bs);
  }
}

// offv: [0,128) offwgt GEMM (BN=256, 1 n-tile) | [128,640) V1 red | [640,768) V2 red
__global__ __launch_bounds__(256)
void offv_k(const unsigned short* Qbf, const unsigned short* owb,
            const float* bias144, float* offwgt,
            const float* Vp1, const float* Vp2, const float* vb1,
            const float* vb2, unsigned short* V1b, unsigned short* V2b) {
  __shared__ __attribute__((aligned(16))) unsigned short As[4096];
  __shared__ __attribute__((aligned(16))) unsigned short Bs[16384];
  int bid = blockIdx.x;
  if (bid < 128) {
    gemm_body<64, 256, 2, 2, 0>(Qbf, owb, bias144, offwgt, nullptr, 144, 256, 256,
                                256, 144, nullptr, nullptr, bid * 64, 0, As, Bs);
  } else if (bid < 640) {
    int e4 = (bid - 128) * 256 + threadIdx.x;
    const float4* P = (const float4*)Vp1;
    float4 a = P[e4], b = P[e4 + 131072];
    float4 bb = *(const float4*)(vb1 + ((e4 << 2) & 255));
    ushort4 u;
    u.x = f2bf(a.x + b.x + bb.x); u.y = f2bf(a.y + b.y + bb.y);
    u.z = f2bf(a.z + b.z + bb.z); u.w = f2bf(a.w + b.w + bb.w);
    ((ushort4*)V1b)[e4] = u;
  } else {
    int e4 = (bid - 640) * 256 + threadIdx.x;
    const float4* P = (const float4*)Vp2;
    float4 a = P[e4], b = P[e4 + 32768], c = P[e4 + 65536], d = P[e4 + 98304];
    float4 bb = *(const float4*)(vb2 + ((e4 << 2) & 255));
    ushort4 u;
    u.x = f2bf(a.x + b.x + c.x + d.x + bb.x);
    u.y = f2bf(a.y + b.y + c.y + d.y + bb.y);
    u.z = f2bf(a.z + b.z + c.z + d.z + bb.z);
    u.w = f2bf(a.w + b.w + c.w + d.w + bb.w);
    ((ushort4*)V2b)[e4] = u;
  }
}

// outA: split-K=2 GEMM acc@out_w -> fp32 partials [2][8192][256]
__global__ __launch_bounds__(256)
void outA_k(const unsigned short* accbf, const unsigned short* out_wb, float* Op) {
  __shared__ __attribute__((aligned(16))) char sm[36864];
  int ks = blockIdx.y;
  gemm_body<32, 256, 1, 4, 4>(accbf + ks * 512, out_wb + ks * 512, nullptr,
                              Op + (size_t)ks * 2097152, nullptr, 256, 512, 1024,
                              1024, 256, nullptr, nullptr, blockIdx.x * 32, 0,
                              (unsigned short*)sm, (unsigned short*)(sm + 4096));
}

// outB: reduce 2 partials + bias + S residual + LN -> Zbf bf16
__global__ __launch_bounds__(256)
void outB_k(const float* __restrict__ Op, const float* __restrict__ S,
            const float* __restrict__ out_b, const float* __restrict__ g,
            const float* __restrict__ be, unsigned short* __restrict__ Zbf) {
  __shared__ float Ls[16][264];
  int q0 = blockIdx.x * 16;
  int b = q0 >> 12, qq = q0 & (NQ - 1);
  int t = threadIdx.x;
  {
    int cs = t >> 2, j = (t & 3) * 4;
    #pragma unroll
    for (int c0 = 0; c0 < 256; c0 += 64) {
      float4 sv = *(const float4*)(S + (((size_t)(b * 256 + c0 + cs)) << 12) + qq + j);
      Ls[j + 0][c0 + cs] = sv.x; Ls[j + 1][c0 + cs] = sv.y;
      Ls[j + 2][c0 + cs] = sv.z; Ls[j + 3][c0 + cs] = sv.w;
    }
  }
  __syncthreads();
  int c = t;
  float bv = out_b[c];
  float val[16];
  #pragma unroll
  for (int r = 0; r < 16; r++) {
    size_t idx = (size_t)(q0 + r) * 256 + c;
    val[r] = Op[idx] + Op[idx + 2097152] + bv + Ls[r][c];
  }
  __syncthreads();
  #pragma unroll
  for (int r = 0; r < 16; r++) Ls[r][c] = val[r];
  __syncthreads();
  int row = t >> 4, lg = t & 15;
  const float* Lr = &Ls[row][lg * 16];
  float s1 = 0.f, s2 = 0.f;
  #pragma unroll
  for (int i = 0; i < 4; i++) {
    float4 t4 = *(const float4*)(Lr + i * 4);
    s1 += t4.x + t4.y + t4.z + t4.w;
    s2 += t4.x * t4.x + t4.y * t4.y + t4.z * t4.z + t4.w * t4.w;
  }
  #pragma unroll
  for (int o = 1; o < 16; o <<= 1) {
    s1 += __shfl_xor(s1, o);
    s2 += __shfl_xor(s2, o);
  }
  float mu = s1 * (1.f / 256.f);
  float var = s2 * (1.f / 256.f) - mu * mu;
  float rs = rsqrtf(var + 1e-5f);
  int gm = q0 + row;
  #pragma unroll
  for (int i = 0; i < 4; i++) {
    int col = lg * 16 + i * 4;
    float4 t4 = *(const float4*)(Lr + i * 4);
    float4 gg = *(const float4*)(g + col);
    float4 bb4 = *(const float4*)(be + col);
    ushort4 ub;
    ub.x = f2bf((t4.x - mu) * rs * gg.x + bb4.x);
    ub.y = f2bf((t4.y - mu) * rs * gg.y + bb4.y);
    ub.z = f2bf((t4.z - mu) * rs * gg.z + bb4.z);
    ub.w = f2bf((t4.w - mu) * rs * gg.w + bb4.w);
    *(ushort4*)(Zbf + (size_t)gm * CC + col) = ub;
  }
}

// fc1: 64x256 tile -> grid (4,128), half the redundant traffic of 64x128
__global__ __launch_bounds__(256)
void fc1_k(const unsigned short* Zbf, const unsigned short* fc1_wb,
           const float* fc1_b, unsigned short* hbf) {
  __shared__ __attribute__((aligned(16))) unsigned short As[4096];
  __shared__ __attribute__((aligned(16))) unsigned short Bs[16384];
  gemm_body<64, 256, 2, 2, 1>(Zbf, fc1_wb, fc1_b, nullptr, hbf, 1024, 256, 256,
                              256, 1024, nullptr, nullptr,
                              blockIdx.y * 64, blockIdx.x * 256, As, Bs);
}

// fc2: fused full-K=1024, 64x64 tile, EPI=2 with bf16 Z residual
__global__ __launch_bounds__(256)
void fc2_k(const unsigned short* hbf, const unsigned short* fc2_wb,
           const float* fc2_b, const unsigned short* Zbf, float* outp) {
  __shared__ __attribute__((aligned(16))) unsigned short As[4096];
  __shared__ __attribute__((aligned(16))) unsigned short Bs[4096];
  gemm_body<64, 64, 2, 2, 2>(hbf, fc2_wb, fc2_b, nullptr, nullptr, 256, 1024,
                             1024, 1024, 256, Zbf, outp,
                             blockIdx.y * 64, blockIdx.x * 64, As, Bs);
}

// ================================================================= sampling
__global__ __launch_bounds__(256)
void sample_k(const float* __restrict__ ow, const float* __restrict__ sim,
              const unsigned short* __restrict__ V0, const unsigned short* __restrict__ V1,
              const unsigned short* __restrict__ V2, unsigned short* __restrict__ acc) {
  int bn = blockIdx.x;
  int q = ((bn & 7) << 10) | (bn >> 3);
  int b = q >> 12, n = q & (NQ - 1);
  int tid = threadIdx.x, head = tid >> 6, lane = tid & 63;
  int half = lane >> 5, l32 = lane & 31;

  __shared__ float s_w[48];
  __shared__ int   s_xy[48][2];
  __shared__ float s_f[48][2];
  __shared__ uint2 s_ow[192];

  if (tid < 48) {
    int hh = tid / 12, pt = tid % 12, l = pt >> 2, mm = pt & 3;
    int oidx = (hh * 3 + l) * 4 + mm;
    float offx = ow[(size_t)q * 144 + oidx * 2 + 0];
    float offy = ow[(size_t)q * 144 + oidx * 2 + 1];
    float refx = ((n & 63) + 0.5f) * (1.f / 64.f);
    float refy = ((n >> 6) + 0.5f) * (1.f / 64.f);
    float gx = tanhf((refx + offx) * 2.f - 1.f);
    float gy = tanhf((refy + offy) * 2.f - 1.f);
    gx = fminf(1.f, fmaxf(-1.f, gx));
    gy = fminf(1.f, fmaxf(-1.f, gy));
    int Wl = 64 >> l;
    float x = (gx + 1.f) * 0.5f * (float)(Wl - 1);
    float y = (gy + 1.f) * 0.5f * (float)(Wl - 1);
    float x0 = floorf(x), y0 = floorf(y);
    s_xy[tid][0] = (int)x0;
    s_xy[tid][1] = (int)y0;
    s_f[tid][0] = x - x0;
    s_f[tid][1] = y - y0;
    s_w[tid] = ow[(size_t)q * 144 + 96 + oidx] * (sim[q] + 0.001f);
  }
  __syncthreads();
  if (tid < 4) {
    float mx = -1e30f;
    #pragma unroll
    for (int i = 0; i < 12; i++) mx = fmaxf(mx, s_w[tid * 12 + i]);
    float e[12], ssum = 0.f;
    #pragma unroll
    for (int i = 0; i < 12; i++) { e[i] = expf(s_w[tid * 12 + i] - mx); ssum += e[i]; }
    float inv = 1.f / ssum;
    #pragma unroll
    for (int i = 0; i < 12; i++) s_w[tid * 12 + i] = e[i] * inv;
  }
  __syncthreads();
  if (tid < 192) {
    int s = tid >> 2, tap = tid & 3;
    int l = (s % 12) >> 2;
    int Wl = 64 >> l;
    int X = s_xy[s][0] + (tap & 1), Y = s_xy[s][1] + (tap >> 1);
    bool valid = (X >= 0 && X < Wl && Y >= 0 && Y < Wl);
    float wx = (tap & 1) ? s_f[s][0] : 1.f - s_f[s][0];
    float wy = (tap >> 1) ? s_f[s][1] : 1.f - s_f[s][1];
    float twt = valid ? s_w[s] * wx * wy : 0.f;
    int Xc = min(max(X, 0), Wl - 1), Yc = min(max(Y, 0), Wl - 1);
    s_ow[tid].x = (unsigned)((Yc * Wl + Xc) << 8);
    s_ow[tid].y = __float_as_uint(twt);
  }
  __syncthreads();

  const unsigned short* B0 = V0 + (size_t)b * 4096 * CC;
  const unsigned short* B1 = V1 + (size_t)b * 1024 * CC;
  const unsigned short* B2 = V2 + (size_t)b * 256 * CC;
  int ch8 = l32 * 8;
  float a0 = 0.f, a1 = 0.f, a2 = 0.f, a3 = 0.f;
  float a4 = 0.f, a5 = 0.f, a6 = 0.f, a7 = 0.f;
  #pragma unroll
  for (int it = 0; it < 24; it++) {
    const unsigned short* base = (it < 8) ? B0 : (it < 16) ? B1 : B2;
    uint2 owv = s_ow[head * 48 + it * 2 + half];
    float w = __uint_as_float(owv.y);
    const uint4 u = *(const uint4*)(base + owv.x + ch8);
    a0 = fmaf(w, __uint_as_float(u.x << 16), a0);
    a1 = fmaf(w, __uint_as_float(u.x & 0xffff0000u), a1);
    a2 = fmaf(w, __uint_as_float(u.y << 16), a2);
    a3 = fmaf(w, __uint_as_float(u.y & 0xffff0000u), a3);
    a4 = fmaf(w, __uint_as_float(u.z << 16), a4);
    a5 = fmaf(w, __uint_as_float(u.z & 0xffff0000u), a5);
    a6 = fmaf(w, __uint_as_float(u.w << 16), a6);
    a7 = fmaf(w, __uint_as_float(u.w & 0xffff0000u), a7);
  }
  a0 += __shfl_xor(a0, 32); a1 += __shfl_xor(a1, 32);
  a2 += __shfl_xor(a2, 32); a3 += __shfl_xor(a3, 32);
  a4 += __shfl_xor(a4, 32); a5 += __shfl_xor(a5, 32);
  a6 += __shfl_xor(a6, 32); a7 += __shfl_xor(a7, 32);
  if (half == 0) {
    uint4 r;
    r.x = (unsigned)f2bf(a0) | ((unsigned)f2bf(a1) << 16);
    r.y = (unsigned)f2bf(a2) | ((unsigned)f2bf(a3) << 16);
    r.z = (unsigned)f2bf(a4) | ((unsigned)f2bf(a5) << 16);
    r.w = (unsigned)f2bf(a6) | ((unsigned)f2bf(a7) << 16);
    *(uint4*)(acc + (size_t)q * 1024 + head * CC + ch8) = r;
  }
}

// ================================================================= launch
extern "C" void kernel_launch(void* const* d_in, const int* in_sizes, int n_in,
                              void* d_out, int out_size, void* d_ws, size_t ws_size,
                              hipStream_t stream) {
  const float* S     = (const float*)d_in[0];
  const float* f0    = (const float*)d_in[1];
  const float* f1    = (const float*)d_in[2];
  const float* f2    = (const float*)d_in[3];
  const float* sim   = (const float*)d_in[4];
  const float* vw0   = (const float*)d_in[5];
  const float* vb0   = (const float*)d_in[6];
  const float* vw1   = (const float*)d_in[7];
  const float* vb1   = (const float*)d_in[8];
  const float* vw2   = (const float*)d_in[9];
  const float* vb2   = (const float*)d_in[10];
  const float* q_w   = (const float*)d_in[11];
  const float* q_b   = (const float*)d_in[12];
  const float* off_w = (const float*)d_in[13];
  const float* off_b = (const float*)d_in[14];
  const float* wgt_w = (const float*)d_in[15];
  const float* wgt_b = (const float*)d_in[16];
  const float* out_w = (const float*)d_in[17];
  const float* out_b = (const float*)d_in[18];
  const float* lnq_g = (const float*)d_in[19];
  const float* lnq_b = (const float*)d_in[20];
  const float* lno_g = (const float*)d_in[21];
  const float* lno_b = (const float*)d_in[22];
  const float* fc1_w = (const float*)d_in[23];
  const float* fc1_b = (const float*)d_in[24];
  const float* fc2_w = (const float*)d_in[25];
  const float* fc2_b = (const float*)d_in[26];

  char* p = (char*)d_ws;
  float* offwgt = (float*)p; p += 4718592;
  float* bias144 = (float*)p; p += 1024;
  float* Pp     = (float*)p; p += 16777216;   // outA partials (2 slices)
  float* Vp1    = (float*)p; p += 4194304;
  float* Vp2    = (float*)p; p += 2097152;
  unsigned short* Sbf   = (unsigned short*)p; p += 4194304;
  unsigned short* Qbf   = (unsigned short*)p; p += 4194304;   // alias Zbf
  unsigned short* accbf = (unsigned short*)p; p += 16777216;  // alias Xf*, hbf
  unsigned short* V0b   = (unsigned short*)p; p += 4194304;
  unsigned short* V1b   = (unsigned short*)p; p += 1048576;
  unsigned short* V2b   = (unsigned short*)p; p += 262144;
  unsigned short* q_wb   = (unsigned short*)p; p += 131072;
  unsigned short* owb    = (unsigned short*)p; p += 131072;
  unsigned short* vw0b   = (unsigned short*)p; p += 131072;
  unsigned short* vw1b   = (unsigned short*)p; p += 262144;
  unsigned short* vw2b   = (unsigned short*)p; p += 524288;
  unsigned short* out_wb = (unsigned short*)p; p += 524288;
  unsigned short* fc1_wb = (unsigned short*)p; p += 524288;
  unsigned short* fc2_wb = (unsigned short*)p; p += 524288;

  unsigned short* Xf0 = accbf;
  unsigned short* Xf1 = accbf + 2097152;
  unsigned short* Xf2 = accbf + 3145728;
  unsigned short* Zbf = Qbf;
  unsigned short* hbf = accbf;
  float* outp = (float*)d_out;

  prep_all_k<<<2944, 256, 0, stream>>>(S, f0, f1, f2, q_w, off_w, wgt_w,
      vw0, vw1, vw2, out_w, fc1_w, fc2_w, off_b, wgt_b,
      Sbf, Xf0, Xf1, Xf2, q_wb, owb, vw0b, vw1b, vw2b, out_wb,
      fc1_wb, fc2_wb, bias144);

  qv_k<<<704, 256, 0, stream>>>(Sbf, q_wb, q_b, lnq_g, lnq_b, Qbf,
      Xf0, Xf1, Xf2, vw0b, vw1b, vw2b, vb0, V0b, Vp1, Vp2);

  offv_k<<<768, 256, 0, stream>>>(Qbf, owb, bias144, offwgt,
      Vp1, Vp2, vb1, vb2, V1b, V2b);

  sample_k<<<8192, 256, 0, stream>>>(offwgt, sim, V0b, V1b, V2b, accbf);

  outA_k<<<dim3(256, 2), 256, 0, stream>>>(accbf, out_wb, Pp);

  outB_k<<<512, 256, 0, stream>>>(Pp, S, out_b, lno_g, lno_b, Zbf);

  fc1_k<<<dim3(4, 128), 256, 0, stream>>>(Zbf, fc1_wb, fc1_b, hbf);

  fc2_k<<<dim3(4, 128), 256, 0, stream>>>(hbf, fc2_wb, fc2_b, Zbf, outp);
}